// Round 12
// baseline (429.740 us; speedup 1.0000x reference)
//
#include <hip/hip_runtime.h>
#include <hip/hip_bf16.h>

// Problem constants
#define DM   1024
#define NHQ  16
#define NKVH 4
#define HDIM 64
#define TTT  64
#define SSS  256
#define NBB  2
#define MROWS 32768   // NBB*SSS*TTT

using short8 = __attribute__((ext_vector_type(8))) short;
using short4v = __attribute__((ext_vector_type(4))) short;
using f32x4  = __attribute__((ext_vector_type(4))) float;

__device__ __forceinline__ short f2bf(float f) {
  union { __hip_bfloat16 h; short s; } u;
  u.h = __float2bfloat16(f);
  return u.s;
}

__device__ __forceinline__ f32x4 mfma16(short8 a, short8 b, f32x4 c) {
  return __builtin_amdgcn_mfma_f32_16x16x32_bf16(a, b, c, 0, 0, 0);
}

__device__ __forceinline__ void gload_lds16(const void* g, void* l) {
  __builtin_amdgcn_global_load_lds(
      (const __attribute__((address_space(1))) void*)g,
      (__attribute__((address_space(3))) void*)l, 16, 0, 0);
}

// ---------------------------------------------------------------
// Kernel 0: merged prep.
// blocks [0,4096): xconv grid-stride (8 rows/block)
// blocks [4096,6656): weight transposes
// ---------------------------------------------------------------
__global__ __launch_bounds__(256) void k_prep(const float* __restrict__ x,
                                              short* __restrict__ xb,
                                              const float* __restrict__ wq,
                                              const float* __restrict__ wk,
                                              const float* __restrict__ wv,
                                              const float* __restrict__ wo,
                                              short* __restrict__ wqkvT,
                                              short* __restrict__ woT) {
  __shared__ float tile[32][33];
  int bid = blockIdx.x;
  if (bid < 4096) {
    float4 v[8];
    #pragma unroll
    for (int i = 0; i < 8; ++i) {
      int r = bid * 8 + i;
      int n = r >> 6, t = r & 63;
      int b = n >> 8, s = n & 255;
      v[i] = ((const float4*)(x + ((size_t)((b * TTT + t) * SSS + s)) * DM))[threadIdx.x];
    }
    #pragma unroll
    for (int i = 0; i < 8; ++i) {
      int r = bid * 8 + i;
      short4 o;
      o.x = f2bf(v[i].x); o.y = f2bf(v[i].y); o.z = f2bf(v[i].z); o.w = f2bf(v[i].w);
      ((short4*)(xb + (size_t)r * DM))[threadIdx.x] = o;
    }
    return;
  }
  bid -= 4096;
  const float* w; short* wt; int cols;
  if (bid < 1024)      { w = wq; wt = wqkvT; cols = 1024; }
  else if (bid < 1280) { w = wk; wt = wqkvT + (size_t)1024 * 1024; cols = 256; bid -= 1024; }
  else if (bid < 1536) { w = wv; wt = wqkvT + (size_t)1280 * 1024; cols = 256; bid -= 1280; }
  else                 { w = wo; wt = woT; cols = 1024; bid -= 1536; }
  int ctiles = cols >> 5;
  int tj = bid % ctiles;
  int td = bid / ctiles;
  int lx = threadIdx.x & 31, ly = threadIdx.x >> 5;
  #pragma unroll
  for (int rr = 0; rr < 32; rr += 8)
    tile[rr + ly][lx] = w[(size_t)(td * 32 + rr + ly) * cols + tj * 32 + lx];
  __syncthreads();
  #pragma unroll
  for (int rr = 0; rr < 32; rr += 8)
    wt[(size_t)(tj * 32 + rr + ly) * 1024 + td * 32 + lx] = f2bf(tile[lx][rr + ly]);
}

// ---------------------------------------------------------------
// Persistent 256x256 GEMM machinery. Same verified 8-phase counted-vmcnt
// schedule; staging takes (base, kt) so the pipeline continues across
// output tiles (prologue of tile j+1 hidden under tail of tile j).
// ---------------------------------------------------------------
#define GEMM_SETUP                                                             \
  const int tid = threadIdx.x, lane = tid & 63, wid = tid >> 6;                \
  const int wr = wid >> 2, wc = wid & 3;                                       \
  const int ln15 = lane & 15, lhi = lane >> 4;                                 \
  const int rsw = ln15 & 7;                                                    \
  const size_t goff = (size_t)(tid >> 3) * 1024                                \
                    + (size_t)(((tid & 7) ^ ((tid >> 3) & 7)) << 3);           \
  auto stA0 = [&](short* lb, const short* base, int kt) {                      \
    gload_lds16(base + goff + kt, lb + tid * 8);                               \
    gload_lds16(base + goff + 65536 + kt, lb + 4096 + tid * 8);                \
  };                                                                           \
  auto stA1 = [&](short* lb, const short* base, int kt) {                      \
    gload_lds16(base + goff + 131072 + kt, lb + 8192 + tid * 8);               \
    gload_lds16(base + goff + 196608 + kt, lb + 12288 + tid * 8);              \
  };                                                                           \
  auto stB = [&](short* lb, const short* base, int kt) {                       \
    gload_lds16(base + goff + kt, lb + 16384 + tid * 8);                       \
    gload_lds16(base + goff + 65536 + kt, lb + 20480 + tid * 8);               \
    gload_lds16(base + goff + 131072 + kt, lb + 24576 + tid * 8);              \
    gload_lds16(base + goff + 196608 + kt, lb + 28672 + tid * 8);              \
  };                                                                           \
  const int sk0 = (lhi ^ rsw) << 3;                                            \
  const int sk1 = ((4 + lhi) ^ rsw) << 3;                                      \
  const short* rA0k0 = sm + (wr * 128 + ln15) * 64 + sk0;                      \
  const short* rA0k1 = sm + (wr * 128 + ln15) * 64 + sk1;                      \
  const short* rB0k0 = sm + 16384 + (wc * 64 + ln15) * 64 + sk0;               \
  const short* rB0k1 = sm + 16384 + (wc * 64 + ln15) * 64 + sk1;               \
  const short* rA1k0 = rA0k0 + 32768;                                          \
  const short* rA1k1 = rA0k1 + 32768;                                          \
  const short* rB1k0 = rB0k0 + 32768;                                          \
  const short* rB1k1 = rB0k1 + 32768;                                          \
  short* buf0 = sm;                                                            \
  short* buf1 = sm + 32768;                                                    \
  f32x4 acc[8][4] = {};

#define PTILE(RAK0, RAK1, RBK0, RBK1, NLB, CLB, IA, ABASE, AKT, IB, BBASE, BKT, VM) \
  {                                                                            \
    short8 a[4], b0[4], b1[4];                                                 \
    _Pragma("unroll") for (int n = 0; n < 4; ++n)                              \
        b0[n] = *(const short8*)(RBK0 + n * 1024);                             \
    _Pragma("unroll") for (int m = 0; m < 4; ++m)                              \
        a[m] = *(const short8*)(RAK0 + m * 1024);                              \
    if (IA) stA0(NLB, ABASE, AKT);                                             \
    __builtin_amdgcn_s_barrier();                                              \
    asm volatile("s_waitcnt lgkmcnt(0)" ::: "memory");                         \
    __builtin_amdgcn_s_setprio(1);                                             \
    _Pragma("unroll") for (int m = 0; m < 4; ++m)                              \
      _Pragma("unroll") for (int n = 0; n < 4; ++n)                            \
          acc[m][n] = mfma16(a[m], b0[n], acc[m][n]);                          \
    __builtin_amdgcn_s_setprio(0);                                             \
    __builtin_amdgcn_s_barrier();                                              \
    _Pragma("unroll") for (int m = 0; m < 4; ++m)                              \
        a[m] = *(const short8*)(RAK0 + 4096 + m * 1024);                       \
    if (IA) stA1(NLB, ABASE, AKT);                                             \
    __builtin_amdgcn_s_barrier();                                              \
    asm volatile("s_waitcnt lgkmcnt(0)" ::: "memory");                         \
    __builtin_amdgcn_s_setprio(1);                                             \
    _Pragma("unroll") for (int m = 0; m < 4; ++m)                              \
      _Pragma("unroll") for (int n = 0; n < 4; ++n)                            \
          acc[4 + m][n] = mfma16(a[m], b0[n], acc[4 + m][n]);                  \
    __builtin_amdgcn_s_setprio(0);                                             \
    __builtin_amdgcn_s_barrier();                                              \
    _Pragma("unroll") for (int n = 0; n < 4; ++n)                              \
        b1[n] = *(const short8*)(RBK1 + n * 1024);                             \
    _Pragma("unroll") for (int m = 0; m < 4; ++m)                              \
        a[m] = *(const short8*)(RAK1 + m * 1024);                              \
    __builtin_amdgcn_s_barrier();                                              \
    asm volatile("s_waitcnt lgkmcnt(0)" ::: "memory");                         \
    __builtin_amdgcn_s_setprio(1);                                             \
    _Pragma("unroll") for (int m = 0; m < 4; ++m)                              \
      _Pragma("unroll") for (int n = 0; n < 4; ++n)                            \
          acc[m][n] = mfma16(a[m], b1[n], acc[m][n]);                          \
    __builtin_amdgcn_s_setprio(0);                                             \
    __builtin_amdgcn_s_barrier();                                              \
    _Pragma("unroll") for (int m = 0; m < 4; ++m)                              \
        a[m] = *(const short8*)(RAK1 + 4096 + m * 1024);                       \
    if (IB) stB(CLB, BBASE, BKT);                                              \
    __builtin_amdgcn_s_barrier();                                              \
    asm volatile("s_waitcnt lgkmcnt(0)" ::: "memory");                         \
    __builtin_amdgcn_s_setprio(1);                                             \
    _Pragma("unroll") for (int m = 0; m < 4; ++m)                              \
      _Pragma("unroll") for (int n = 0; n < 4; ++n)                            \
          acc[4 + m][n] = mfma16(a[m], b1[n], acc[4 + m][n]);                  \
    __builtin_amdgcn_s_setprio(0);                                             \
    if ((VM) == 4)      asm volatile("s_waitcnt vmcnt(4)" ::: "memory");       \
    else if ((VM) == 0) asm volatile("s_waitcnt vmcnt(0)" ::: "memory");       \
    __builtin_amdgcn_s_barrier();                                              \
  }

#define PGEMM_TILES(MORE, AC, BC, AN, BN)                                      \
  PTILE(rA0k0, rA0k1, rB0k0, rB0k1, buf1, buf0, (j > 0), AC, 64, true, BC, 128, 4) \
  PTILE(rA1k0, rA1k1, rB1k0, rB1k1, buf0, buf1, true, AC, 128, true, BC, 192, 4)   \
  for (int gg = 1; gg < 7; ++gg) {                                             \
    PTILE(rA0k0, rA0k1, rB0k0, rB0k1, buf1, buf0, true, AC, (2 * gg + 1) * 64, \
          true, BC, (2 * gg + 2) * 64, 4)                                      \
    PTILE(rA1k0, rA1k1, rB1k0, rB1k1, buf0, buf1, true, AC, (2 * gg + 2) * 64, \
          true, BC, (2 * gg + 3) * 64, 4)                                      \
  }                                                                            \
  PTILE(rA0k0, rA0k1, rB0k0, rB0k1, buf1, buf0, true, AC, 960, (MORE), BN, 0,  \
        (MORE) ? 4 : 0)                                                        \
  PTILE(rA1k0, rA1k1, rB1k0, rB1k1, buf0, buf1, (MORE), AN, 0, (MORE), BN, 64, \
        (MORE) ? 4 : -1)

// ---------------------------------------------------------------
// Kernel 1: persistent QKV projection + RMSNorm + RoPE. grid 256, 3 tiles/block.
// Epilogue runs in 4 passes through buf1's A-region (dead during epilogue).
// ---------------------------------------------------------------
__global__ __launch_bounds__(512) void k_qkv(
    const short* __restrict__ xb, const short* __restrict__ wt,
    const float* __restrict__ qscale, const float* __restrict__ kscale,
    const float* __restrict__ rcos, const float* __restrict__ rsin,
    short* __restrict__ qb, short* __restrict__ kb, short* __restrict__ vb) {
  __shared__ __align__(16) short sm[65536];   // 128 KiB
  const int bid = blockIdx.x;
  GEMM_SETUP
  short* epi = sm + 32768;                    // buf1 A region (32 KiB scratch)
  int swz = (bid & 7) * 96 + (bid >> 3);
  int tn = swz % 6, tm = swz / 6;
  const short* Ac = xb + (size_t)tm * 262144;
  const short* Bc = wt + (size_t)tn * 262144;
  // prologue: tiles 0 and 1 of first GEMM
  stA0(buf0, Ac, 0); stA1(buf0, Ac, 0); stB(buf0, Bc, 0);
  stA0(buf1, Ac, 64); stA1(buf1, Ac, 64); stB(buf1, Bc, 64);
  asm volatile("s_waitcnt vmcnt(8)" ::: "memory");
  __builtin_amdgcn_s_barrier();
  for (int j = 0; j < 3; ++j) {
    const bool more = (j < 2);
    int swzn = (bid & 7) * 96 + (j + 1) * 32 + (bid >> 3);
    int tnn = swzn % 6, tmn = swzn / 6;
    const short* An = more ? (xb + (size_t)tmn * 262144) : Ac;
    const short* Bn = more ? (wt + (size_t)tnn * 262144) : Bc;
    PGEMM_TILES(more, Ac, Bc, An, Bn)
    // ---- epilogue (4 passes of 64 rows via epi) ----
    if (tn < 5) {
      const float* scale = (tn < 4) ? qscale : kscale;
      float sc[4];
      #pragma unroll
      for (int n = 0; n < 4; ++n) sc[n] = scale[n * 16 + ln15];
      #pragma unroll
      for (int p = 0; p < 4; ++p) {
        if (wr == (p >> 1)) {
          #pragma unroll
          for (int mm = 0; mm < 4; ++mm) {
            const int m = (p & 1) * 4 + mm;
            #pragma unroll
            for (int jj = 0; jj < 4; ++jj) {
              float ss = 0.f;
              #pragma unroll
              for (int n = 0; n < 4; ++n) { float v = acc[m][n][jj]; ss += v * v; }
              #pragma unroll
              for (int off = 8; off; off >>= 1) ss += __shfl_xor(ss, off, 64);
              float rms = rsqrtf(ss * (1.f / 64.f) + 1e-6f);
              int t = mm * 16 + lhi * 4 + jj;     // == local row; global row & 63
              #pragma unroll
              for (int n = 0; n < 2; ++n) {
                int i = n * 16 + ln15;
                float cs = rcos[t * 32 + i], sn = rsin[t * 32 + i];
                float v1 = acc[m][n][jj] * rms * sc[n];
                float v2 = acc[m][n + 2][jj] * rms * sc[n + 2];
                epi[t * 256 + wc * 64 + i]      = f2bf(v1 * cs - v2 * sn);
                epi[t * 256 + wc * 64 + i + 32] = f2bf(v1 * sn + v2 * cs);
              }
            }
          }
        }
        asm volatile("s_waitcnt lgkmcnt(0)" ::: "memory");
        __builtin_amdgcn_s_barrier();
        {
          int row = tid >> 3, seg = tid & 7;
          int r = tm * 256 + p * 64 + row;
          const uint4* src = (const uint4*)(epi + row * 256 + seg * 32);
          short* dst = (tn < 4) ? (qb + (size_t)r * 1024 + tn * 256 + seg * 32)
                                : (kb + (size_t)r * 256 + seg * 32);
          uint4* d4 = (uint4*)dst;
          #pragma unroll
          for (int i2 = 0; i2 < 4; ++i2) d4[i2] = src[i2];
        }
        __builtin_amdgcn_s_barrier();
      }
    } else {
      #pragma unroll
      for (int p = 0; p < 4; ++p) {
        if (wr == (p >> 1)) {
          #pragma unroll
          for (int mm = 0; mm < 4; ++mm) {
            const int m = (p & 1) * 4 + mm;
            #pragma unroll
            for (int n = 0; n < 4; ++n)
              #pragma unroll
              for (int jj = 0; jj < 4; ++jj)
                epi[(mm * 16 + lhi * 4 + jj) * 256 + wc * 64 + n * 16 + ln15]
                    = f2bf(acc[m][n][jj]);
          }
        }
        asm volatile("s_waitcnt lgkmcnt(0)" ::: "memory");
        __builtin_amdgcn_s_barrier();
        {
          int row = tid >> 3, seg = tid & 7;
          int r = tm * 256 + p * 64 + row;
          uint4* d4 = (uint4*)(vb + (size_t)r * 256 + seg * 32);
          const uint4* src = (const uint4*)(epi + row * 256 + seg * 32);
          #pragma unroll
          for (int i2 = 0; i2 < 4; ++i2) d4[i2] = src[i2];
        }
        __builtin_amdgcn_s_barrier();
      }
    }
    if (more) {
      #pragma unroll
      for (int m = 0; m < 8; ++m)
        #pragma unroll
        for (int n = 0; n < 4; ++n) acc[m][n] = (f32x4){0.f, 0.f, 0.f, 0.f};
      Ac = An; Bc = Bn; tm = tmn; tn = tnn;
    }
  }
}

// ---------------------------------------------------------------
// Kernel 2: attention, TWO sequences per block (round-11 form, unchanged)
// ---------------------------------------------------------------
__global__ __launch_bounds__(512) void k_attn(const short* __restrict__ qb,
                                              const short* __restrict__ kb,
                                              const short* __restrict__ vb,
                                              short* __restrict__ ob) {
  __shared__ __align__(16) short Vt[2][256 * 72];
  __shared__ __align__(16) short Ps[8][64 * 72];
  const int n0 = blockIdx.x * 2;
  const int tid = threadIdx.x, lane = tid & 63, wid = tid >> 6;
  const int ln15 = lane & 15, lhi = lane >> 4;
  short8 vr0[4], vr1[4];
  {
    const short* vrow0 = vb + ((size_t)(n0 * 64 + lane)) * 256;
    const short* vrow1 = vrow0 + 64 * 256;
    #pragma unroll
    for (int i = 0; i < 4; ++i) vr1[i] = *(const short8*)(vrow1 + wid * 32 + i * 8);
    #pragma unroll
    for (int i = 0; i < 4; ++i) vr0[i] = *(const short8*)(vrow0 + wid * 32 + i * 8);
  }
  #pragma unroll
  for (int i = 0; i < 4; ++i) {
    int d = wid * 32 + i * 8;
    #pragma unroll
    for (int e = 0; e < 8; ++e) Vt[0][(d + e) * 72 + lane] = vr0[i][e];
  }
  short* Pt = &Ps[wid][0];
  #pragma unroll
  for (int ss = 0; ss < 2; ++ss) {
    const int n = n0 + ss;
    if (ss == 1) {
      #pragma unroll
      for (int i = 0; i < 4; ++i) {
        int d = wid * 32 + i * 8;
        #pragma unroll
        for (int e = 0; e < 8; ++e) Vt[1][(d + e) * 72 + lane] = vr1[i][e];
      }
    }
    short8 aq[2][4][2];
    #pragma unroll
    for (int hh = 0; hh < 2; ++hh)
      #pragma unroll
      for (int nn = 0; nn < 4; ++nn)
        #pragma unroll
        for (int kk = 0; kk < 2; ++kk)
          aq[hh][nn][kk] = *(const short8*)(qb + ((size_t)(n * 64 + nn * 16 + ln15)) * 1024
                                               + (wid + hh * 8) * 64 + kk * 32 + lhi * 8);
    __syncthreads();
    const short* Vts = &Vt[ss][0];
    #pragma unroll
    for (int hh = 0; hh < 2; ++hh) {
      const int h = wid + hh * 8;
      const int kvh = h >> 2;
      short8 bk[4][2];
      #pragma unroll
      for (int m = 0; m < 4; ++m)
        #pragma unroll
        for (int kk = 0; kk < 2; ++kk)
          bk[m][kk] = *(const short8*)(kb + ((size_t)(n * 64 + m * 16 + ln15)) * 256
                                          + kvh * 64 + kk * 32 + lhi * 8);
      f32x4 sa[4][4] = {};
      __builtin_amdgcn_s_setprio(1);
      #pragma unroll
      for (int kk = 0; kk < 2; ++kk)
        #pragma unroll
        for (int m = 0; m < 4; ++m)
          #pragma unroll
          for (int nn = 0; nn < 4; ++nn)
            sa[m][nn] = mfma16(bk[m][kk], aq[hh][nn][kk], sa[m][nn]);
      __builtin_amdgcn_s_setprio(0);
      #pragma unroll
      for (int m = 0; m < 4; ++m)
        #pragma unroll
        for (int nn = 0; nn < 4; ++nn)
          #pragma unroll
          for (int j = 0; j < 4; ++j) {
            float e2 = __expf(sa[m][nn][j] * 0.005f);
            float cap = 50.f * (e2 - 1.f) * __builtin_amdgcn_rcpf(e2 + 1.f);
            int scur = m * 16 + lhi * 4 + j, tcur = nn * 16 + ln15;
            sa[m][nn][j] = (scur <= tcur) ? cap : -1e30f;
          }
      float inv[4];
      #pragma unroll
      for (int nn = 0; nn < 4; ++nn) {
        float mx = -3e38f;
        #pragma unroll
        for (int m = 0; m < 4; ++m)
          #pragma unroll
          for (int j = 0; j < 4; ++j) mx = fmaxf(mx, sa[m][nn][j]);
        mx = fmaxf(mx, __shfl_xor(mx, 16, 64));
        mx = fmaxf(mx, __shfl_xor(mx, 32, 64));
        float sum = 0.f;
        #pragma unroll
        for (int m = 0; m < 4; ++m)
          #pragma unroll
          for (int j = 0; j < 4; ++j) {
            float e = __expf(sa[m][nn][j] - mx);
            sa[m][nn][j] = e; sum += e;
          }
        sum += __shfl_xor(sum, 16, 64);
        sum += __shfl_xor(sum, 32, 64);
        inv[nn] = __builtin_amdgcn_rcpf(sum);
      }
      #pragma unroll
      for (int nn = 0; nn < 4; ++nn)
        #pragma unroll
        for (int m = 0; m < 4; ++m) {
          short4v w;
          #pragma unroll
          for (int j = 0; j < 4; ++j) w[j] = f2bf(sa[m][nn][j] * inv[nn]);
          *(short4v*)(Pt + (nn * 16 + ln15) * 72 + m * 16 + lhi * 4) = w;
        }
      short8 ap[4][2], bv[4][2];
      #pragma unroll
      for (int m = 0; m < 4; ++m)
        #pragma unroll
        for (int kk = 0; kk < 2; ++kk)
          ap[m][kk] = *(const short8*)(Pt + (m * 16 + ln15) * 72 + kk * 32 + lhi * 8);
      #pragma unroll
      for (int nn = 0; nn < 4; ++nn)
        #pragma unroll
        for (int kk = 0; kk < 2; ++kk)
          bv[nn][kk] = *(const short8*)(Vts + (kvh * 64 + nn * 16 + ln15) * 72 + kk * 32 + lhi * 8);
      f32x4 oa[4][4] = {};
      __builtin_amdgcn_s_setprio(1);
      #pragma unroll
      for (int kk = 0; kk < 2; ++kk)
        #pragma unroll
        for (int m = 0; m < 4; ++m)
          #pragma unroll
          for (int nn = 0; nn < 4; ++nn)
            oa[m][nn] = mfma16(ap[m][kk], bv[nn][kk], oa[m][nn]);
      __builtin_amdgcn_s_setprio(0);
      #pragma unroll
      for (int m = 0; m < 4; ++m)
        #pragma unroll
        for (int nn = 0; nn < 4; ++nn)
          #pragma unroll
          for (int j = 0; j < 4; ++j)
            Pt[(m * 16 + lhi * 4 + j) * 72 + nn * 16 + ln15] = f2bf(oa[m][nn][j]);
      #pragma unroll
      for (int c = 0; c < 8; ++c)
        *(uint4*)(ob + ((size_t)(n * 64 + lane)) * 1024 + h * 64 + c * 8)
            = *(const uint4*)(Pt + lane * 72 + c * 8);
    }
  }
}

// ---------------------------------------------------------------
// Kernel 3: persistent output projection. grid 256, 2 tiles/block.
// Epilogue in 8 passes of 32 f32 rows via buf1 A-region.
// ---------------------------------------------------------------
__global__ __launch_bounds__(512) void k_out(const short* __restrict__ ab,
                                             const short* __restrict__ wt,
                                             float* __restrict__ out) {
  __shared__ __align__(16) short sm[65536];   // 128 KiB
  const int bid = blockIdx.x;
  GEMM_SETUP
  float* epif = (float*)(sm + 32768);         // 32 KiB scratch
  int swz = (bid & 7) * 64 + (bid >> 3);
  int tn = swz & 3, tm = swz >> 2;
  const short* Ac = ab + (size_t)tm * 262144;
  const short* Bc = wt + (size_t)tn * 262144;
  stA0(buf0, Ac, 0); stA1(buf0, Ac, 0); stB(buf0, Bc, 0);
  stA0(buf1, Ac, 64); stA1(buf1, Ac, 64); stB(buf1, Bc, 64);
  asm volatile("s_waitcnt vmcnt(8)" ::: "memory");
  __builtin_amdgcn_s_barrier();
  for (int j = 0; j < 2; ++j) {
    const bool more = (j < 1);
    int swzn = (bid & 7) * 64 + 32 + (bid >> 3);
    int tnn = swzn & 3, tmn = swzn >> 2;
    const short* An = more ? (ab + (size_t)tmn * 262144) : Ac;
    const short* Bn = more ? (wt + (size_t)tnn * 262144) : Bc;
    PGEMM_TILES(more, Ac, Bc, An, Bn)
    // ---- epilogue (8 passes of 32 rows) ----
    #pragma unroll
    for (int p = 0; p < 8; ++p) {
      if (wr == (p >> 2)) {
        #pragma unroll
        for (int mm = 0; mm < 2; ++mm) {
          const int m = (p & 3) * 2 + mm;
          #pragma unroll
          for (int n = 0; n < 4; ++n)
            #pragma unroll
            for (int jj = 0; jj < 4; ++jj)
              epif[(mm * 16 + lhi * 4 + jj) * 256 + wc * 64 + n * 16 + ln15]
                  = acc[m][n][jj];
        }
      }
      asm volatile("s_waitcnt lgkmcnt(0)" ::: "memory");
      __builtin_amdgcn_s_barrier();
      {
        int row = tid >> 4, seg = tid & 15;
        int r = tm * 256 + p * 32 + row;
        int nseq = r >> 6, t = r & 63;
        int b = nseq >> 8, s = nseq & 255;
        float* dst = out + ((size_t)((b * TTT + t) * SSS + s)) * DM + tn * 256 + seg * 16;
        const float4* src = (const float4*)(epif + row * 256 + seg * 16);
        #pragma unroll
        for (int i2 = 0; i2 < 4; ++i2) ((float4*)dst)[i2] = src[i2];
      }
      __builtin_amdgcn_s_barrier();
    }
    if (more) {
      #pragma unroll
      for (int m = 0; m < 8; ++m)
        #pragma unroll
        for (int n = 0; n < 4; ++n) acc[m][n] = (f32x4){0.f, 0.f, 0.f, 0.f};
      Ac = An; Bc = Bn; tm = tmn; tn = tnn;
    }
  }
}

// ---------------------------------------------------------------
extern "C" void kernel_launch(void* const* d_in, const int* in_sizes, int n_in,
                              void* d_out, int out_size, void* d_ws, size_t ws_size,
                              hipStream_t stream) {
  const float* x  = (const float*)d_in[0];
  const float* wq = (const float*)d_in[1];
  const float* wk = (const float*)d_in[2];
  const float* wv = (const float*)d_in[3];
  const float* wo = (const float*)d_in[4];
  const float* qs = (const float*)d_in[5];
  const float* ks = (const float*)d_in[6];
  const float* rc = (const float*)d_in[7];
  const float* rs = (const float*)d_in[8];
  float* out = (float*)d_out;
  char* ws = (char*)d_ws;

  short* xb    = (short*)(ws);                      // 64 MiB; later aliased as attn-out
  short* wqkvT = (short*)(ws + 67108864);           // 3 MiB  (1536 x 1024)
  short* woT   = (short*)(ws + 70254592);           // 2 MiB  (1024 x 1024)
  short* qb    = (short*)(ws + 72351744);           // 64 MiB
  short* kb    = (short*)(ws + 139460608);          // 16 MiB
  short* vb    = (short*)(ws + 156237824);          // 16 MiB
  short* ob    = xb;                                // alias: xb dead after k_qkv

  k_prep<<<6656, 256, 0, stream>>>(x, xb, wq, wk, wv, wo, wqkvT, woT);
  k_qkv<<<256, 512, 0, stream>>>(xb, wqkvT, qs, ks, rc, rs, qb, kb, vb);
  k_attn<<<256, 512, 0, stream>>>(qb, kb, vb, ob);
  k_out<<<256, 512, 0, stream>>>(ob, woT, out);
}

// Round 13
// 318.613 us; speedup vs baseline: 1.3488x; 1.3488x over previous
//
#include <hip/hip_runtime.h>
#include <hip/hip_bf16.h>

// Problem constants
#define DM   1024
#define NHQ  16
#define NKVH 4
#define HDIM 64
#define TTT  64
#define SSS  256
#define NBB  2
#define MROWS 32768   // NBB*SSS*TTT

using short8 = __attribute__((ext_vector_type(8))) short;
using short4v = __attribute__((ext_vector_type(4))) short;
using f32x4  = __attribute__((ext_vector_type(4))) float;

__device__ __forceinline__ short f2bf(float f) {
  union { __hip_bfloat16 h; short s; } u;
  u.h = __float2bfloat16(f);
  return u.s;
}

__device__ __forceinline__ f32x4 mfma16(short8 a, short8 b, f32x4 c) {
  return __builtin_amdgcn_mfma_f32_16x16x32_bf16(a, b, c, 0, 0, 0);
}

__device__ __forceinline__ void gload_lds16(const void* g, void* l) {
  __builtin_amdgcn_global_load_lds(
      (const __attribute__((address_space(1))) void*)g,
      (__attribute__((address_space(3))) void*)l, 16, 0, 0);
}

// ---------------------------------------------------------------
// Kernel 0: merged prep.
// blocks [0,4096): xconv grid-stride (8 rows/block)
// blocks [4096,6656): weight transposes
// ---------------------------------------------------------------
__global__ __launch_bounds__(256) void k_prep(const float* __restrict__ x,
                                              short* __restrict__ xb,
                                              const float* __restrict__ wq,
                                              const float* __restrict__ wk,
                                              const float* __restrict__ wv,
                                              const float* __restrict__ wo,
                                              short* __restrict__ wqkvT,
                                              short* __restrict__ woT) {
  __shared__ float tile[32][33];
  int bid = blockIdx.x;
  if (bid < 4096) {
    float4 v[8];
    #pragma unroll
    for (int i = 0; i < 8; ++i) {
      int r = bid * 8 + i;
      int n = r >> 6, t = r & 63;
      int b = n >> 8, s = n & 255;
      v[i] = ((const float4*)(x + ((size_t)((b * TTT + t) * SSS + s)) * DM))[threadIdx.x];
    }
    #pragma unroll
    for (int i = 0; i < 8; ++i) {
      int r = bid * 8 + i;
      short4 o;
      o.x = f2bf(v[i].x); o.y = f2bf(v[i].y); o.z = f2bf(v[i].z); o.w = f2bf(v[i].w);
      ((short4*)(xb + (size_t)r * DM))[threadIdx.x] = o;
    }
    return;
  }
  bid -= 4096;
  const float* w; short* wt; int cols;
  if (bid < 1024)      { w = wq; wt = wqkvT; cols = 1024; }
  else if (bid < 1280) { w = wk; wt = wqkvT + (size_t)1024 * 1024; cols = 256; bid -= 1024; }
  else if (bid < 1536) { w = wv; wt = wqkvT + (size_t)1280 * 1024; cols = 256; bid -= 1280; }
  else                 { w = wo; wt = woT; cols = 1024; bid -= 1536; }
  int ctiles = cols >> 5;
  int tj = bid % ctiles;
  int td = bid / ctiles;
  int lx = threadIdx.x & 31, ly = threadIdx.x >> 5;
  #pragma unroll
  for (int rr = 0; rr < 32; rr += 8)
    tile[rr + ly][lx] = w[(size_t)(td * 32 + rr + ly) * cols + tj * 32 + lx];
  __syncthreads();
  #pragma unroll
  for (int rr = 0; rr < 32; rr += 8)
    wt[(size_t)(tj * 32 + rr + ly) * 1024 + td * 32 + lx] = f2bf(tile[lx][rr + ly]);
}

// ---------------------------------------------------------------
// 256x256 GEMM core (round-6 form, unchanged)
// ---------------------------------------------------------------
#define TILE(RAK0, RAK1, RBK0, RBK1, NLB, CLB, G, IA, IB, VM)                  \
  {                                                                            \
    short8 a[4], b0[4], b1[4];                                                 \
    _Pragma("unroll") for (int n = 0; n < 4; ++n)                              \
        b0[n] = *(const short8*)(RBK0 + n * 1024);                             \
    _Pragma("unroll") for (int m = 0; m < 4; ++m)                              \
        a[m] = *(const short8*)(RAK0 + m * 1024);                              \
    if (IA) stA0(NLB, (G + 1) * 64);                                           \
    __builtin_amdgcn_s_barrier();                                              \
    asm volatile("s_waitcnt lgkmcnt(0)" ::: "memory");                         \
    __builtin_amdgcn_s_setprio(1);                                             \
    _Pragma("unroll") for (int m = 0; m < 4; ++m)                              \
      _Pragma("unroll") for (int n = 0; n < 4; ++n)                            \
          acc[m][n] = mfma16(a[m], b0[n], acc[m][n]);                          \
    __builtin_amdgcn_s_setprio(0);                                             \
    __builtin_amdgcn_s_barrier();                                              \
    _Pragma("unroll") for (int m = 0; m < 4; ++m)                              \
        a[m] = *(const short8*)(RAK0 + 4096 + m * 1024);                       \
    if (IA) stA1(NLB, (G + 1) * 64);                                           \
    __builtin_amdgcn_s_barrier();                                              \
    asm volatile("s_waitcnt lgkmcnt(0)" ::: "memory");                         \
    __builtin_amdgcn_s_setprio(1);                                             \
    _Pragma("unroll") for (int m = 0; m < 4; ++m)                              \
      _Pragma("unroll") for (int n = 0; n < 4; ++n)                            \
          acc[4 + m][n] = mfma16(a[m], b0[n], acc[4 + m][n]);                  \
    __builtin_amdgcn_s_setprio(0);                                             \
    __builtin_amdgcn_s_barrier();                                              \
    _Pragma("unroll") for (int n = 0; n < 4; ++n)                              \
        b1[n] = *(const short8*)(RBK1 + n * 1024);                             \
    _Pragma("unroll") for (int m = 0; m < 4; ++m)                              \
        a[m] = *(const short8*)(RAK1 + m * 1024);                              \
    __builtin_amdgcn_s_barrier();                                              \
    asm volatile("s_waitcnt lgkmcnt(0)" ::: "memory");                         \
    __builtin_amdgcn_s_setprio(1);                                             \
    _Pragma("unroll") for (int m = 0; m < 4; ++m)                              \
      _Pragma("unroll") for (int n = 0; n < 4; ++n)                            \
          acc[m][n] = mfma16(a[m], b1[n], acc[m][n]);                          \
    __builtin_amdgcn_s_setprio(0);                                             \
    __builtin_amdgcn_s_barrier();                                              \
    _Pragma("unroll") for (int m = 0; m < 4; ++m)                              \
        a[m] = *(const short8*)(RAK1 + 4096 + m * 1024);                       \
    if (IB) stB(CLB, (G + 2) * 64);                                            \
    __builtin_amdgcn_s_barrier();                                              \
    asm volatile("s_waitcnt lgkmcnt(0)" ::: "memory");                         \
    __builtin_amdgcn_s_setprio(1);                                             \
    _Pragma("unroll") for (int m = 0; m < 4; ++m)                              \
      _Pragma("unroll") for (int n = 0; n < 4; ++n)                            \
          acc[4 + m][n] = mfma16(a[m], b1[n], acc[4 + m][n]);                  \
    __builtin_amdgcn_s_setprio(0);                                             \
    if (VM == 4)      asm volatile("s_waitcnt vmcnt(4)" ::: "memory");         \
    else if (VM == 0) asm volatile("s_waitcnt vmcnt(0)" ::: "memory");         \
    __builtin_amdgcn_s_barrier();                                              \
  }

__device__ __forceinline__ void gemm256(const short* __restrict__ Ab,
                                        const short* __restrict__ Bb,
                                        short* __restrict__ sm,
                                        f32x4 (&acc)[8][4]) {
  const int tid = threadIdx.x, lane = tid & 63, wid = tid >> 6;
  const int wr = wid >> 2, wc = wid & 3;
  const int ln15 = lane & 15, lhi = lane >> 4;
  const int rsw = ln15 & 7;
  const int row_t = tid >> 3;
  const int sw = ((tid & 7) ^ (row_t & 7)) << 3;
  const short* pA0 = Ab + (size_t)row_t * 1024 + sw;
  const short* pA1 = pA0 + (size_t)64 * 1024;
  const short* pA2 = pA0 + (size_t)128 * 1024;
  const short* pA3 = pA0 + (size_t)192 * 1024;
  const short* pB0 = Bb + (size_t)row_t * 1024 + sw;
  const short* pB1 = pB0 + (size_t)64 * 1024;
  const short* pB2 = pB0 + (size_t)128 * 1024;
  const short* pB3 = pB0 + (size_t)192 * 1024;
  auto stA0 = [&](short* lb, int kt) {
    gload_lds16(pA0 + kt, lb + tid * 8);
    gload_lds16(pA1 + kt, lb + 4096 + tid * 8);
  };
  auto stA1 = [&](short* lb, int kt) {
    gload_lds16(pA2 + kt, lb + 8192 + tid * 8);
    gload_lds16(pA3 + kt, lb + 12288 + tid * 8);
  };
  auto stB = [&](short* lb, int kt) {
    gload_lds16(pB0 + kt, lb + 16384 + tid * 8);
    gload_lds16(pB1 + kt, lb + 20480 + tid * 8);
    gload_lds16(pB2 + kt, lb + 24576 + tid * 8);
    gload_lds16(pB3 + kt, lb + 28672 + tid * 8);
  };
  const int sk0 = (lhi ^ rsw) << 3;
  const int sk1 = ((4 + lhi) ^ rsw) << 3;
  const short* rA0k0 = sm + (wr * 128 + ln15) * 64 + sk0;
  const short* rA0k1 = sm + (wr * 128 + ln15) * 64 + sk1;
  const short* rB0k0 = sm + 16384 + (wc * 64 + ln15) * 64 + sk0;
  const short* rB0k1 = sm + 16384 + (wc * 64 + ln15) * 64 + sk1;
  const short* rA1k0 = rA0k0 + 32768;
  const short* rA1k1 = rA0k1 + 32768;
  const short* rB1k0 = rB0k0 + 32768;
  const short* rB1k1 = rB0k1 + 32768;
  short* buf0 = sm;
  short* buf1 = sm + 32768;
  stA0(buf0, 0); stA1(buf0, 0); stB(buf0, 0);
  stA0(buf1, 64); stA1(buf1, 64); stB(buf1, 64);
  asm volatile("s_waitcnt vmcnt(8)" ::: "memory");
  __builtin_amdgcn_s_barrier();
  TILE(rA0k0, rA0k1, rB0k0, rB0k1, buf1, buf0, 0, 0, 1, 4)
  TILE(rA1k0, rA1k1, rB1k0, rB1k1, buf0, buf1, 1, 1, 1, 4)
  for (int gg = 1; gg < 7; ++gg) {
    const int g0 = gg * 2;
    TILE(rA0k0, rA0k1, rB0k0, rB0k1, buf1, buf0, g0, 1, 1, 4)
    TILE(rA1k0, rA1k1, rB1k0, rB1k1, buf0, buf1, g0 + 1, 1, 1, 4)
  }
  TILE(rA0k0, rA0k1, rB0k0, rB0k1, buf1, buf0, 14, 1, 0, 0)
  TILE(rA1k0, rA1k1, rB1k0, rB1k1, buf0, buf1, 15, 0, 0, -1)
}

// ---------------------------------------------------------------
// Kernel 1: QKV projection + RMSNorm + RoPE (round-11 form)
// ---------------------------------------------------------------
__global__ __launch_bounds__(512) void k_qkv(
    const short* __restrict__ xb, const short* __restrict__ wt,
    const float* __restrict__ qscale, const float* __restrict__ kscale,
    const float* __restrict__ rcos, const float* __restrict__ rsin,
    short* __restrict__ qb, short* __restrict__ kb, short* __restrict__ vb) {
  __shared__ __align__(16) short sm[65536];   // 128 KiB
  const int bid = blockIdx.x;
  const int swz = (bid & 7) * 96 + (bid >> 3);
  const int tn = swz % 6, tm = swz / 6;
  f32x4 acc[8][4] = {};
  gemm256(xb + (size_t)tm * 256 * 1024, wt + (size_t)tn * 256 * 1024, sm, acc);

  const int tid = threadIdx.x, lane = tid & 63, wid = tid >> 6;
  const int wr = wid >> 2, wc = wid & 3;
  const int ln15 = lane & 15, lhi = lane >> 4;
  short* ot = sm;
  if (tn < 5) {
    const float* scale = (tn < 4) ? qscale : kscale;
    float sc[4];
    #pragma unroll
    for (int n = 0; n < 4; ++n) sc[n] = scale[n * 16 + ln15];
    #pragma unroll
    for (int m = 0; m < 8; ++m) {
      #pragma unroll
      for (int j = 0; j < 4; ++j) {
        float ss = 0.f;
        #pragma unroll
        for (int n = 0; n < 4; ++n) { float v = acc[m][n][j]; ss += v * v; }
        #pragma unroll
        for (int off = 8; off; off >>= 1) ss += __shfl_xor(ss, off, 64);
        float rms = rsqrtf(ss * (1.f / 64.f) + 1e-6f);
        int rl = wr * 128 + m * 16 + lhi * 4 + j;
        int t = (tm * 256 + rl) & 63;
        #pragma unroll
        for (int n = 0; n < 2; ++n) {
          int i = n * 16 + ln15;
          float cs = rcos[t * 32 + i], sn = rsin[t * 32 + i];
          float v1 = acc[m][n][j] * rms * sc[n];
          float v2 = acc[m][n + 2][j] * rms * sc[n + 2];
          ot[rl * 256 + wc * 64 + i]      = f2bf(v1 * cs - v2 * sn);
          ot[rl * 256 + wc * 64 + i + 32] = f2bf(v1 * sn + v2 * cs);
        }
      }
    }
  } else {
    #pragma unroll
    for (int m = 0; m < 8; ++m)
      #pragma unroll
      for (int n = 0; n < 4; ++n)
        #pragma unroll
        for (int j = 0; j < 4; ++j) {
          int rl = wr * 128 + m * 16 + lhi * 4 + j;
          ot[rl * 256 + wc * 64 + n * 16 + ln15] = f2bf(acc[m][n][j]);
        }
  }
  __syncthreads();
  {
    int row = tid >> 1, half = tid & 1;
    int r = tm * 256 + row;
    const uint4* src = (const uint4*)(ot + row * 256 + half * 128);
    short* dst;
    if (tn < 4)       dst = qb + (size_t)r * 1024 + tn * 256 + half * 128;
    else if (tn == 4) dst = kb + (size_t)r * 256 + half * 128;
    else              dst = vb + (size_t)r * 256 + half * 128;
    uint4* d4 = (uint4*)dst;
    #pragma unroll
    for (int i = 0; i < 16; ++i) d4[i] = src[i];
  }
}

// ---------------------------------------------------------------
// Kernel 2: attention, TWO sequences per block (round-11 form)
// ---------------------------------------------------------------
__global__ __launch_bounds__(512) void k_attn(const short* __restrict__ qb,
                                              const short* __restrict__ kb,
                                              const short* __restrict__ vb,
                                              short* __restrict__ ob) {
  __shared__ __align__(16) short Vt[2][256 * 72];   // 72 KiB  [c][s] per seq
  __shared__ __align__(16) short Ps[8][64 * 72];    // 72 KiB  per-wave P / O staging
  const int n0 = blockIdx.x * 2;
  const int tid = threadIdx.x, lane = tid & 63, wid = tid >> 6;
  const int ln15 = lane & 15, lhi = lane >> 4;
  short8 vr0[4], vr1[4];
  {
    const short* vrow0 = vb + ((size_t)(n0 * 64 + lane)) * 256;
    const short* vrow1 = vrow0 + 64 * 256;
    #pragma unroll
    for (int i = 0; i < 4; ++i) vr1[i] = *(const short8*)(vrow1 + wid * 32 + i * 8);
    #pragma unroll
    for (int i = 0; i < 4; ++i) vr0[i] = *(const short8*)(vrow0 + wid * 32 + i * 8);
  }
  #pragma unroll
  for (int i = 0; i < 4; ++i) {
    int d = wid * 32 + i * 8;
    #pragma unroll
    for (int e = 0; e < 8; ++e) Vt[0][(d + e) * 72 + lane] = vr0[i][e];
  }
  short* Pt = &Ps[wid][0];
  #pragma unroll
  for (int ss = 0; ss < 2; ++ss) {
    const int n = n0 + ss;
    if (ss == 1) {
      #pragma unroll
      for (int i = 0; i < 4; ++i) {
        int d = wid * 32 + i * 8;
        #pragma unroll
        for (int e = 0; e < 8; ++e) Vt[1][(d + e) * 72 + lane] = vr1[i][e];
      }
    }
    short8 aq[2][4][2];
    #pragma unroll
    for (int hh = 0; hh < 2; ++hh)
      #pragma unroll
      for (int nn = 0; nn < 4; ++nn)
        #pragma unroll
        for (int kk = 0; kk < 2; ++kk)
          aq[hh][nn][kk] = *(const short8*)(qb + ((size_t)(n * 64 + nn * 16 + ln15)) * 1024
                                               + (wid + hh * 8) * 64 + kk * 32 + lhi * 8);
    __syncthreads();
    const short* Vts = &Vt[ss][0];
    #pragma unroll
    for (int hh = 0; hh < 2; ++hh) {
      const int h = wid + hh * 8;
      const int kvh = h >> 2;
      short8 bk[4][2];
      #pragma unroll
      for (int m = 0; m < 4; ++m)
        #pragma unroll
        for (int kk = 0; kk < 2; ++kk)
          bk[m][kk] = *(const short8*)(kb + ((size_t)(n * 64 + m * 16 + ln15)) * 256
                                          + kvh * 64 + kk * 32 + lhi * 8);
      f32x4 sa[4][4] = {};
      __builtin_amdgcn_s_setprio(1);
      #pragma unroll
      for (int kk = 0; kk < 2; ++kk)
        #pragma unroll
        for (int m = 0; m < 4; ++m)
          #pragma unroll
          for (int nn = 0; nn < 4; ++nn)
            sa[m][nn] = mfma16(bk[m][kk], aq[hh][nn][kk], sa[m][nn]);
      __builtin_amdgcn_s_setprio(0);
      #pragma unroll
      for (int m = 0; m < 4; ++m)
        #pragma unroll
        for (int nn = 0; nn < 4; ++nn)
          #pragma unroll
          for (int j = 0; j < 4; ++j) {
            float e2 = __expf(sa[m][nn][j] * 0.005f);
            float cap = 50.f * (e2 - 1.f) * __builtin_amdgcn_rcpf(e2 + 1.f);
            int scur = m * 16 + lhi * 4 + j, tcur = nn * 16 + ln15;
            sa[m][nn][j] = (scur <= tcur) ? cap : -1e30f;
          }
      float inv[4];
      #pragma unroll
      for (int nn = 0; nn < 4; ++nn) {
        float mx = -3e38f;
        #pragma unroll
        for (int m = 0; m < 4; ++m)
          #pragma unroll
          for (int j = 0; j < 4; ++j) mx = fmaxf(mx, sa[m][nn][j]);
        mx = fmaxf(mx, __shfl_xor(mx, 16, 64));
        mx = fmaxf(mx, __shfl_xor(mx, 32, 64));
        float sum = 0.f;
        #pragma unroll
        for (int m = 0; m < 4; ++m)
          #pragma unroll
          for (int j = 0; j < 4; ++j) {
            float e = __expf(sa[m][nn][j] - mx);
            sa[m][nn][j] = e; sum += e;
          }
        sum += __shfl_xor(sum, 16, 64);
        sum += __shfl_xor(sum, 32, 64);
        inv[nn] = __builtin_amdgcn_rcpf(sum);
      }
      #pragma unroll
      for (int nn = 0; nn < 4; ++nn)
        #pragma unroll
        for (int m = 0; m < 4; ++m) {
          short4v w;
          #pragma unroll
          for (int j = 0; j < 4; ++j) w[j] = f2bf(sa[m][nn][j] * inv[nn]);
          *(short4v*)(Pt + (nn * 16 + ln15) * 72 + m * 16 + lhi * 4) = w;
        }
      short8 ap[4][2], bv[4][2];
      #pragma unroll
      for (int m = 0; m < 4; ++m)
        #pragma unroll
        for (int kk = 0; kk < 2; ++kk)
          ap[m][kk] = *(const short8*)(Pt + (m * 16 + ln15) * 72 + kk * 32 + lhi * 8);
      #pragma unroll
      for (int nn = 0; nn < 4; ++nn)
        #pragma unroll
        for (int kk = 0; kk < 2; ++kk)
          bv[nn][kk] = *(const short8*)(Vts + (kvh * 64 + nn * 16 + ln15) * 72 + kk * 32 + lhi * 8);
      f32x4 oa[4][4] = {};
      __builtin_amdgcn_s_setprio(1);
      #pragma unroll
      for (int kk = 0; kk < 2; ++kk)
        #pragma unroll
        for (int m = 0; m < 4; ++m)
          #pragma unroll
          for (int nn = 0; nn < 4; ++nn)
            oa[m][nn] = mfma16(ap[m][kk], bv[nn][kk], oa[m][nn]);
      __builtin_amdgcn_s_setprio(0);
      #pragma unroll
      for (int m = 0; m < 4; ++m)
        #pragma unroll
        for (int nn = 0; nn < 4; ++nn)
          #pragma unroll
          for (int j = 0; j < 4; ++j)
            Pt[(m * 16 + lhi * 4 + j) * 72 + nn * 16 + ln15] = f2bf(oa[m][nn][j]);
      #pragma unroll
      for (int c = 0; c < 8; ++c)
        *(uint4*)(ob + ((size_t)(n * 64 + lane)) * 1024 + h * 64 + c * 8)
            = *(const uint4*)(Pt + lane * 72 + c * 8);
    }
  }
}

// ---------------------------------------------------------------
// Kernel 3: output projection + scatter to (B,T,S,D) f32 (round-11 form)
// ---------------------------------------------------------------
__global__ __launch_bounds__(512) void k_out(const short* __restrict__ ab,
                                             const short* __restrict__ wt,
                                             float* __restrict__ out) {
  __shared__ __align__(16) short sm[65536];   // 128 KiB
  const int bid = blockIdx.x;
  const int swz = (bid & 7) * 64 + (bid >> 3);
  const int tn = swz & 3, tm = swz >> 2;
  f32x4 acc[8][4] = {};
  gemm256(ab + (size_t)tm * 256 * 1024, wt + (size_t)tn * 256 * 1024, sm, acc);

  const int tid = threadIdx.x, lane = tid & 63, wid = tid >> 6;
  const int wr = wid >> 2, wc = wid & 3;
  const int ln15 = lane & 15, lhi = lane >> 4;
  float* of = (float*)sm;
  #pragma unroll
  for (int ch = 0; ch < 2; ++ch) {
    if (wr == ch) {
      #pragma unroll
      for (int m = 0; m < 8; ++m)
        #pragma unroll
        for (int n = 0; n < 4; ++n)
          #pragma unroll
          for (int j = 0; j < 4; ++j)
            of[(m * 16 + lhi * 4 + j) * 256 + wc * 64 + n * 16 + ln15] = acc[m][n][j];
    }
    __syncthreads();
    {
      int row = tid >> 2, q4 = tid & 3;
      int r = tm * 256 + ch * 128 + row;
      int nseq = r >> 6, t = r & 63;
      int b = nseq >> 8, s = nseq & 255;
      float* dst = out + ((size_t)((b * TTT + t) * SSS + s)) * DM + tn * 256 + q4 * 64;
      const float4* src = (const float4*)(of + row * 256 + q4 * 64);
      float4* d4 = (float4*)dst;
      #pragma unroll
      for (int i = 0; i < 16; ++i) d4[i] = src[i];
    }
    __syncthreads();
  }
}

// ---------------------------------------------------------------
extern "C" void kernel_launch(void* const* d_in, const int* in_sizes, int n_in,
                              void* d_out, int out_size, void* d_ws, size_t ws_size,
                              hipStream_t stream) {
  const float* x  = (const float*)d_in[0];
  const float* wq = (const float*)d_in[1];
  const float* wk = (const float*)d_in[2];
  const float* wv = (const float*)d_in[3];
  const float* wo = (const float*)d_in[4];
  const float* qs = (const float*)d_in[5];
  const float* ks = (const float*)d_in[6];
  const float* rc = (const float*)d_in[7];
  const float* rs = (const float*)d_in[8];
  float* out = (float*)d_out;
  char* ws = (char*)d_ws;

  short* xb    = (short*)(ws);                      // 64 MiB; later aliased as attn-out
  short* wqkvT = (short*)(ws + 67108864);           // 3 MiB  (1536 x 1024)
  short* woT   = (short*)(ws + 70254592);           // 2 MiB  (1024 x 1024)
  short* qb    = (short*)(ws + 72351744);           // 64 MiB
  short* kb    = (short*)(ws + 139460608);          // 16 MiB
  short* vb    = (short*)(ws + 156237824);          // 16 MiB
  short* ob    = xb;                                // alias: xb dead after k_qkv

  k_prep<<<6656, 256, 0, stream>>>(x, xb, wq, wk, wv, wo, wqkvT, woT);
  k_qkv<<<768, 512, 0, stream>>>(xb, wqkvT, qs, ks, rc, rs, qb, kb, vb);
  k_attn<<<256, 512, 0, stream>>>(qb, kb, vb, ob);
  k_out<<<512, 512, 0, stream>>>(ob, woT, out);
}

// Round 14
// 315.140 us; speedup vs baseline: 1.3636x; 1.0110x over previous
//
#include <hip/hip_runtime.h>
#include <hip/hip_bf16.h>

// Problem constants
#define DM   1024
#define NHQ  16
#define NKVH 4
#define HDIM 64
#define TTT  64
#define SSS  256
#define NBB  2
#define MROWS 32768   // NBB*SSS*TTT

using short8 = __attribute__((ext_vector_type(8))) short;
using short4v = __attribute__((ext_vector_type(4))) short;
using f32x4  = __attribute__((ext_vector_type(4))) float;

__device__ __forceinline__ short f2bf(float f) {
  union { __hip_bfloat16 h; short s; } u;
  u.h = __float2bfloat16(f);
  return u.s;
}

__device__ __forceinline__ f32x4 mfma16(short8 a, short8 b, f32x4 c) {
  return __builtin_amdgcn_mfma_f32_16x16x32_bf16(a, b, c, 0, 0, 0);
}

__device__ __forceinline__ void gload_lds16(const void* g, void* l) {
  __builtin_amdgcn_global_load_lds(
      (const __attribute__((address_space(1))) void*)g,
      (__attribute__((address_space(3))) void*)l, 16, 0, 0);
}

// ---------------------------------------------------------------
// Kernel 0: merged prep.
// blocks [0,4096): xconv grid-stride (8 rows/block)
// blocks [4096,6656): weight transposes
// ---------------------------------------------------------------
__global__ __launch_bounds__(256) void k_prep(const float* __restrict__ x,
                                              short* __restrict__ xb,
                                              const float* __restrict__ wq,
                                              const float* __restrict__ wk,
                                              const float* __restrict__ wv,
                                              const float* __restrict__ wo,
                                              short* __restrict__ wqkvT,
                                              short* __restrict__ woT) {
  __shared__ float tile[32][33];
  int bid = blockIdx.x;
  if (bid < 4096) {
    float4 v[8];
    #pragma unroll
    for (int i = 0; i < 8; ++i) {
      int r = bid * 8 + i;
      int n = r >> 6, t = r & 63;
      int b = n >> 8, s = n & 255;
      v[i] = ((const float4*)(x + ((size_t)((b * TTT + t) * SSS + s)) * DM))[threadIdx.x];
    }
    #pragma unroll
    for (int i = 0; i < 8; ++i) {
      int r = bid * 8 + i;
      short4 o;
      o.x = f2bf(v[i].x); o.y = f2bf(v[i].y); o.z = f2bf(v[i].z); o.w = f2bf(v[i].w);
      ((short4*)(xb + (size_t)r * DM))[threadIdx.x] = o;
    }
    return;
  }
  bid -= 4096;
  const float* w; short* wt; int cols;
  if (bid < 1024)      { w = wq; wt = wqkvT; cols = 1024; }
  else if (bid < 1280) { w = wk; wt = wqkvT + (size_t)1024 * 1024; cols = 256; bid -= 1024; }
  else if (bid < 1536) { w = wv; wt = wqkvT + (size_t)1280 * 1024; cols = 256; bid -= 1280; }
  else                 { w = wo; wt = woT; cols = 1024; bid -= 1536; }
  int ctiles = cols >> 5;
  int tj = bid % ctiles;
  int td = bid / ctiles;
  int lx = threadIdx.x & 31, ly = threadIdx.x >> 5;
  #pragma unroll
  for (int rr = 0; rr < 32; rr += 8)
    tile[rr + ly][lx] = w[(size_t)(td * 32 + rr + ly) * cols + tj * 32 + lx];
  __syncthreads();
  #pragma unroll
  for (int rr = 0; rr < 32; rr += 8)
    wt[(size_t)(tj * 32 + rr + ly) * 1024 + td * 32 + lx] = f2bf(tile[lx][rr + ly]);
}

// ---------------------------------------------------------------
// 256x256 GEMM core (round-6 form, unchanged)
// ---------------------------------------------------------------
#define TILE(RAK0, RAK1, RBK0, RBK1, NLB, CLB, G, IA, IB, VM)                  \
  {                                                                            \
    short8 a[4], b0[4], b1[4];                                                 \
    _Pragma("unroll") for (int n = 0; n < 4; ++n)                              \
        b0[n] = *(const short8*)(RBK0 + n * 1024);                             \
    _Pragma("unroll") for (int m = 0; m < 4; ++m)                              \
        a[m] = *(const short8*)(RAK0 + m * 1024);                              \
    if (IA) stA0(NLB, (G + 1) * 64);                                           \
    __builtin_amdgcn_s_barrier();                                              \
    asm volatile("s_waitcnt lgkmcnt(0)" ::: "memory");                         \
    __builtin_amdgcn_s_setprio(1);                                             \
    _Pragma("unroll") for (int m = 0; m < 4; ++m)                              \
      _Pragma("unroll") for (int n = 0; n < 4; ++n)                            \
          acc[m][n] = mfma16(a[m], b0[n], acc[m][n]);                          \
    __builtin_amdgcn_s_setprio(0);                                             \
    __builtin_amdgcn_s_barrier();                                              \
    _Pragma("unroll") for (int m = 0; m < 4; ++m)                              \
        a[m] = *(const short8*)(RAK0 + 4096 + m * 1024);                       \
    if (IA) stA1(NLB, (G + 1) * 64);                                           \
    __builtin_amdgcn_s_barrier();                                              \
    asm volatile("s_waitcnt lgkmcnt(0)" ::: "memory");                         \
    __builtin_amdgcn_s_setprio(1);                                             \
    _Pragma("unroll") for (int m = 0; m < 4; ++m)                              \
      _Pragma("unroll") for (int n = 0; n < 4; ++n)                            \
          acc[4 + m][n] = mfma16(a[m], b0[n], acc[4 + m][n]);                  \
    __builtin_amdgcn_s_setprio(0);                                             \
    __builtin_amdgcn_s_barrier();                                              \
    _Pragma("unroll") for (int n = 0; n < 4; ++n)                              \
        b1[n] = *(const short8*)(RBK1 + n * 1024);                             \
    _Pragma("unroll") for (int m = 0; m < 4; ++m)                              \
        a[m] = *(const short8*)(RAK1 + m * 1024);                              \
    __builtin_amdgcn_s_barrier();                                              \
    asm volatile("s_waitcnt lgkmcnt(0)" ::: "memory");                         \
    __builtin_amdgcn_s_setprio(1);                                             \
    _Pragma("unroll") for (int m = 0; m < 4; ++m)                              \
      _Pragma("unroll") for (int n = 0; n < 4; ++n)                            \
          acc[m][n] = mfma16(a[m], b1[n], acc[m][n]);                          \
    __builtin_amdgcn_s_setprio(0);                                             \
    __builtin_amdgcn_s_barrier();                                              \
    _Pragma("unroll") for (int m = 0; m < 4; ++m)                              \
        a[m] = *(const short8*)(RAK1 + 4096 + m * 1024);                       \
    if (IB) stB(CLB, (G + 2) * 64);                                            \
    __builtin_amdgcn_s_barrier();                                              \
    asm volatile("s_waitcnt lgkmcnt(0)" ::: "memory");                         \
    __builtin_amdgcn_s_setprio(1);                                             \
    _Pragma("unroll") for (int m = 0; m < 4; ++m)                              \
      _Pragma("unroll") for (int n = 0; n < 4; ++n)                            \
          acc[4 + m][n] = mfma16(a[m], b1[n], acc[4 + m][n]);                  \
    __builtin_amdgcn_s_setprio(0);                                             \
    if (VM == 4)      asm volatile("s_waitcnt vmcnt(4)" ::: "memory");         \
    else if (VM == 0) asm volatile("s_waitcnt vmcnt(0)" ::: "memory");         \
    __builtin_amdgcn_s_barrier();                                              \
  }

__device__ __forceinline__ void gemm256(const short* __restrict__ Ab,
                                        const short* __restrict__ Bb,
                                        short* __restrict__ sm,
                                        f32x4 (&acc)[8][4]) {
  const int tid = threadIdx.x, lane = tid & 63, wid = tid >> 6;
  const int wr = wid >> 2, wc = wid & 3;
  const int ln15 = lane & 15, lhi = lane >> 4;
  const int rsw = ln15 & 7;
  const int row_t = tid >> 3;
  const int sw = ((tid & 7) ^ (row_t & 7)) << 3;
  const short* pA0 = Ab + (size_t)row_t * 1024 + sw;
  const short* pA1 = pA0 + (size_t)64 * 1024;
  const short* pA2 = pA0 + (size_t)128 * 1024;
  const short* pA3 = pA0 + (size_t)192 * 1024;
  const short* pB0 = Bb + (size_t)row_t * 1024 + sw;
  const short* pB1 = pB0 + (size_t)64 * 1024;
  const short* pB2 = pB0 + (size_t)128 * 1024;
  const short* pB3 = pB0 + (size_t)192 * 1024;
  auto stA0 = [&](short* lb, int kt) {
    gload_lds16(pA0 + kt, lb + tid * 8);
    gload_lds16(pA1 + kt, lb + 4096 + tid * 8);
  };
  auto stA1 = [&](short* lb, int kt) {
    gload_lds16(pA2 + kt, lb + 8192 + tid * 8);
    gload_lds16(pA3 + kt, lb + 12288 + tid * 8);
  };
  auto stB = [&](short* lb, int kt) {
    gload_lds16(pB0 + kt, lb + 16384 + tid * 8);
    gload_lds16(pB1 + kt, lb + 20480 + tid * 8);
    gload_lds16(pB2 + kt, lb + 24576 + tid * 8);
    gload_lds16(pB3 + kt, lb + 28672 + tid * 8);
  };
  const int sk0 = (lhi ^ rsw) << 3;
  const int sk1 = ((4 + lhi) ^ rsw) << 3;
  const short* rA0k0 = sm + (wr * 128 + ln15) * 64 + sk0;
  const short* rA0k1 = sm + (wr * 128 + ln15) * 64 + sk1;
  const short* rB0k0 = sm + 16384 + (wc * 64 + ln15) * 64 + sk0;
  const short* rB0k1 = sm + 16384 + (wc * 64 + ln15) * 64 + sk1;
  const short* rA1k0 = rA0k0 + 32768;
  const short* rA1k1 = rA0k1 + 32768;
  const short* rB1k0 = rB0k0 + 32768;
  const short* rB1k1 = rB0k1 + 32768;
  short* buf0 = sm;
  short* buf1 = sm + 32768;
  stA0(buf0, 0); stA1(buf0, 0); stB(buf0, 0);
  stA0(buf1, 64); stA1(buf1, 64); stB(buf1, 64);
  asm volatile("s_waitcnt vmcnt(8)" ::: "memory");
  __builtin_amdgcn_s_barrier();
  TILE(rA0k0, rA0k1, rB0k0, rB0k1, buf1, buf0, 0, 0, 1, 4)
  TILE(rA1k0, rA1k1, rB1k0, rB1k1, buf0, buf1, 1, 1, 1, 4)
  for (int gg = 1; gg < 7; ++gg) {
    const int g0 = gg * 2;
    TILE(rA0k0, rA0k1, rB0k0, rB0k1, buf1, buf0, g0, 1, 1, 4)
    TILE(rA1k0, rA1k1, rB1k0, rB1k1, buf0, buf1, g0 + 1, 1, 1, 4)
  }
  TILE(rA0k0, rA0k1, rB0k0, rB0k1, buf1, buf0, 14, 1, 0, 0)
  TILE(rA1k0, rA1k1, rB1k0, rB1k1, buf0, buf1, 15, 0, 0, -1)
}

// ---------------------------------------------------------------
// Kernel 1: QKV projection + RMSNorm + RoPE.
// Epilogue scratch padded: stride 264 shorts (528 B) breaks the 8-way
// bank conflict of the 512 B row stride. LDS 132 KiB (still 1 block/CU).
// ---------------------------------------------------------------
__global__ __launch_bounds__(512) void k_qkv(
    const short* __restrict__ xb, const short* __restrict__ wt,
    const float* __restrict__ qscale, const float* __restrict__ kscale,
    const float* __restrict__ rcos, const float* __restrict__ rsin,
    short* __restrict__ qb, short* __restrict__ kb, short* __restrict__ vb) {
  __shared__ __align__(16) short sm[67584];   // 132 KiB (GEMM uses first 128 KiB)
  const int bid = blockIdx.x;
  const int swz = (bid & 7) * 96 + (bid >> 3);
  const int tn = swz % 6, tm = swz / 6;
  f32x4 acc[8][4] = {};
  gemm256(xb + (size_t)tm * 256 * 1024, wt + (size_t)tn * 256 * 1024, sm, acc);

  const int tid = threadIdx.x, lane = tid & 63, wid = tid >> 6;
  const int wr = wid >> 2, wc = wid & 3;
  const int ln15 = lane & 15, lhi = lane >> 4;
  short* ot = sm;                             // [256][264] padded
  if (tn < 5) {
    const float* scale = (tn < 4) ? qscale : kscale;
    float sc[4];
    #pragma unroll
    for (int n = 0; n < 4; ++n) sc[n] = scale[n * 16 + ln15];
    #pragma unroll
    for (int m = 0; m < 8; ++m) {
      #pragma unroll
      for (int j = 0; j < 4; ++j) {
        float ss = 0.f;
        #pragma unroll
        for (int n = 0; n < 4; ++n) { float v = acc[m][n][j]; ss += v * v; }
        #pragma unroll
        for (int off = 8; off; off >>= 1) ss += __shfl_xor(ss, off, 64);
        float rms = rsqrtf(ss * (1.f / 64.f) + 1e-6f);
        int rl = wr * 128 + m * 16 + lhi * 4 + j;
        int t = (tm * 256 + rl) & 63;
        #pragma unroll
        for (int n = 0; n < 2; ++n) {
          int i = n * 16 + ln15;
          float cs = rcos[t * 32 + i], sn = rsin[t * 32 + i];
          float v1 = acc[m][n][j] * rms * sc[n];
          float v2 = acc[m][n + 2][j] * rms * sc[n + 2];
          ot[rl * 264 + wc * 64 + i]      = f2bf(v1 * cs - v2 * sn);
          ot[rl * 264 + wc * 64 + i + 32] = f2bf(v1 * sn + v2 * cs);
        }
      }
    }
  } else {
    #pragma unroll
    for (int m = 0; m < 8; ++m)
      #pragma unroll
      for (int n = 0; n < 4; ++n)
        #pragma unroll
        for (int j = 0; j < 4; ++j) {
          int rl = wr * 128 + m * 16 + lhi * 4 + j;
          ot[rl * 264 + wc * 64 + n * 16 + ln15] = f2bf(acc[m][n][j]);
        }
  }
  __syncthreads();
  {
    int row = tid >> 1, half = tid & 1;
    int r = tm * 256 + row;
    const uint4* src = (const uint4*)(ot + row * 264 + half * 128);
    short* dst;
    if (tn < 4)       dst = qb + (size_t)r * 1024 + tn * 256 + half * 128;
    else if (tn == 4) dst = kb + (size_t)r * 256 + half * 128;
    else              dst = vb + (size_t)r * 256 + half * 128;
    uint4* d4 = (uint4*)dst;
    #pragma unroll
    for (int i = 0; i < 16; ++i) d4[i] = src[i];
  }
}

// ---------------------------------------------------------------
// Kernel 2: attention, TWO sequences per block (round-11 form, unchanged)
// ---------------------------------------------------------------
__global__ __launch_bounds__(512) void k_attn(const short* __restrict__ qb,
                                              const short* __restrict__ kb,
                                              const short* __restrict__ vb,
                                              short* __restrict__ ob) {
  __shared__ __align__(16) short Vt[2][256 * 72];   // 72 KiB  [c][s] per seq
  __shared__ __align__(16) short Ps[8][64 * 72];    // 72 KiB  per-wave P / O staging
  const int n0 = blockIdx.x * 2;
  const int tid = threadIdx.x, lane = tid & 63, wid = tid >> 6;
  const int ln15 = lane & 15, lhi = lane >> 4;
  short8 vr0[4], vr1[4];
  {
    const short* vrow0 = vb + ((size_t)(n0 * 64 + lane)) * 256;
    const short* vrow1 = vrow0 + 64 * 256;
    #pragma unroll
    for (int i = 0; i < 4; ++i) vr1[i] = *(const short8*)(vrow1 + wid * 32 + i * 8);
    #pragma unroll
    for (int i = 0; i < 4; ++i) vr0[i] = *(const short8*)(vrow0 + wid * 32 + i * 8);
  }
  #pragma unroll
  for (int i = 0; i < 4; ++i) {
    int d = wid * 32 + i * 8;
    #pragma unroll
    for (int e = 0; e < 8; ++e) Vt[0][(d + e) * 72 + lane] = vr0[i][e];
  }
  short* Pt = &Ps[wid][0];
  #pragma unroll
  for (int ss = 0; ss < 2; ++ss) {
    const int n = n0 + ss;
    if (ss == 1) {
      #pragma unroll
      for (int i = 0; i < 4; ++i) {
        int d = wid * 32 + i * 8;
        #pragma unroll
        for (int e = 0; e < 8; ++e) Vt[1][(d + e) * 72 + lane] = vr1[i][e];
      }
    }
    short8 aq[2][4][2];
    #pragma unroll
    for (int hh = 0; hh < 2; ++hh)
      #pragma unroll
      for (int nn = 0; nn < 4; ++nn)
        #pragma unroll
        for (int kk = 0; kk < 2; ++kk)
          aq[hh][nn][kk] = *(const short8*)(qb + ((size_t)(n * 64 + nn * 16 + ln15)) * 1024
                                               + (wid + hh * 8) * 64 + kk * 32 + lhi * 8);
    __syncthreads();
    const short* Vts = &Vt[ss][0];
    #pragma unroll
    for (int hh = 0; hh < 2; ++hh) {
      const int h = wid + hh * 8;
      const int kvh = h >> 2;
      short8 bk[4][2];
      #pragma unroll
      for (int m = 0; m < 4; ++m)
        #pragma unroll
        for (int kk = 0; kk < 2; ++kk)
          bk[m][kk] = *(const short8*)(kb + ((size_t)(n * 64 + m * 16 + ln15)) * 256
                                          + kvh * 64 + kk * 32 + lhi * 8);
      f32x4 sa[4][4] = {};
      __builtin_amdgcn_s_setprio(1);
      #pragma unroll
      for (int kk = 0; kk < 2; ++kk)
        #pragma unroll
        for (int m = 0; m < 4; ++m)
          #pragma unroll
          for (int nn = 0; nn < 4; ++nn)
            sa[m][nn] = mfma16(bk[m][kk], aq[hh][nn][kk], sa[m][nn]);
      __builtin_amdgcn_s_setprio(0);
      #pragma unroll
      for (int m = 0; m < 4; ++m)
        #pragma unroll
        for (int nn = 0; nn < 4; ++nn)
          #pragma unroll
          for (int j = 0; j < 4; ++j) {
            float e2 = __expf(sa[m][nn][j] * 0.005f);
            float cap = 50.f * (e2 - 1.f) * __builtin_amdgcn_rcpf(e2 + 1.f);
            int scur = m * 16 + lhi * 4 + j, tcur = nn * 16 + ln15;
            sa[m][nn][j] = (scur <= tcur) ? cap : -1e30f;
          }
      float inv[4];
      #pragma unroll
      for (int nn = 0; nn < 4; ++nn) {
        float mx = -3e38f;
        #pragma unroll
        for (int m = 0; m < 4; ++m)
          #pragma unroll
          for (int j = 0; j < 4; ++j) mx = fmaxf(mx, sa[m][nn][j]);
        mx = fmaxf(mx, __shfl_xor(mx, 16, 64));
        mx = fmaxf(mx, __shfl_xor(mx, 32, 64));
        float sum = 0.f;
        #pragma unroll
        for (int m = 0; m < 4; ++m)
          #pragma unroll
          for (int j = 0; j < 4; ++j) {
            float e = __expf(sa[m][nn][j] - mx);
            sa[m][nn][j] = e; sum += e;
          }
        sum += __shfl_xor(sum, 16, 64);
        sum += __shfl_xor(sum, 32, 64);
        inv[nn] = __builtin_amdgcn_rcpf(sum);
      }
      #pragma unroll
      for (int nn = 0; nn < 4; ++nn)
        #pragma unroll
        for (int m = 0; m < 4; ++m) {
          short4v w;
          #pragma unroll
          for (int j = 0; j < 4; ++j) w[j] = f2bf(sa[m][nn][j] * inv[nn]);
          *(short4v*)(Pt + (nn * 16 + ln15) * 72 + m * 16 + lhi * 4) = w;
        }
      short8 ap[4][2], bv[4][2];
      #pragma unroll
      for (int m = 0; m < 4; ++m)
        #pragma unroll
        for (int kk = 0; kk < 2; ++kk)
          ap[m][kk] = *(const short8*)(Pt + (m * 16 + ln15) * 72 + kk * 32 + lhi * 8);
      #pragma unroll
      for (int nn = 0; nn < 4; ++nn)
        #pragma unroll
        for (int kk = 0; kk < 2; ++kk)
          bv[nn][kk] = *(const short8*)(Vts + (kvh * 64 + nn * 16 + ln15) * 72 + kk * 32 + lhi * 8);
      f32x4 oa[4][4] = {};
      __builtin_amdgcn_s_setprio(1);
      #pragma unroll
      for (int kk = 0; kk < 2; ++kk)
        #pragma unroll
        for (int m = 0; m < 4; ++m)
          #pragma unroll
          for (int nn = 0; nn < 4; ++nn)
            oa[m][nn] = mfma16(ap[m][kk], bv[nn][kk], oa[m][nn]);
      __builtin_amdgcn_s_setprio(0);
      #pragma unroll
      for (int m = 0; m < 4; ++m)
        #pragma unroll
        for (int nn = 0; nn < 4; ++nn)
          #pragma unroll
          for (int j = 0; j < 4; ++j)
            Pt[(m * 16 + lhi * 4 + j) * 72 + nn * 16 + ln15] = f2bf(oa[m][nn][j]);
      #pragma unroll
      for (int c = 0; c < 8; ++c)
        *(uint4*)(ob + ((size_t)(n * 64 + lane)) * 1024 + h * 64 + c * 8)
            = *(const uint4*)(Pt + lane * 72 + c * 8);
    }
  }
}

// ---------------------------------------------------------------
// Kernel 3: output projection + scatter to (B,T,S,D) f32.
// Epilogue scratch padded: stride 260 f32 (1040 B) -> lhi rows split
// across bank halves (4-way -> ~2-way). LDS 130 KiB.
// ---------------------------------------------------------------
__global__ __launch_bounds__(512) void k_out(const short* __restrict__ ab,
                                             const short* __restrict__ wt,
                                             float* __restrict__ out) {
  __shared__ __align__(16) short sm[66560];   // 130 KiB (GEMM uses first 128 KiB)
  const int bid = blockIdx.x;
  const int swz = (bid & 7) * 64 + (bid >> 3);
  const int tn = swz & 3, tm = swz >> 2;
  f32x4 acc[8][4] = {};
  gemm256(ab + (size_t)tm * 256 * 1024, wt + (size_t)tn * 256 * 1024, sm, acc);

  const int tid = threadIdx.x, lane = tid & 63, wid = tid >> 6;
  const int wr = wid >> 2, wc = wid & 3;
  const int ln15 = lane & 15, lhi = lane >> 4;
  float* of = (float*)sm;                     // [128][260] padded
  #pragma unroll
  for (int ch = 0; ch < 2; ++ch) {
    if (wr == ch) {
      #pragma unroll
      for (int m = 0; m < 8; ++m)
        #pragma unroll
        for (int n = 0; n < 4; ++n)
          #pragma unroll
          for (int j = 0; j < 4; ++j)
            of[(m * 16 + lhi * 4 + j) * 260 + wc * 64 + n * 16 + ln15] = acc[m][n][j];
    }
    __syncthreads();
    {
      int row = tid >> 2, q4 = tid & 3;
      int r = tm * 256 + ch * 128 + row;
      int nseq = r >> 6, t = r & 63;
      int b = nseq >> 8, s = nseq & 255;
      float* dst = out + ((size_t)((b * TTT + t) * SSS + s)) * DM + tn * 256 + q4 * 64;
      const float4* src = (const float4*)(of + row * 260 + q4 * 64);
      float4* d4 = (float4*)dst;
      #pragma unroll
      for (int i = 0; i < 16; ++i) d4[i] = src[i];
    }
    __syncthreads();
  }
}

// ---------------------------------------------------------------
extern "C" void kernel_launch(void* const* d_in, const int* in_sizes, int n_in,
                              void* d_out, int out_size, void* d_ws, size_t ws_size,
                              hipStream_t stream) {
  const float* x  = (const float*)d_in[0];
  const float* wq = (const float*)d_in[1];
  const float* wk = (const float*)d_in[2];
  const float* wv = (const float*)d_in[3];
  const float* wo = (const float*)d_in[4];
  const float* qs = (const float*)d_in[5];
  const float* ks = (const float*)d_in[6];
  const float* rc = (const float*)d_in[7];
  const float* rs = (const float*)d_in[8];
  float* out = (float*)d_out;
  char* ws = (char*)d_ws;

  short* xb    = (short*)(ws);                      // 64 MiB; later aliased as attn-out
  short* wqkvT = (short*)(ws + 67108864);           // 3 MiB  (1536 x 1024)
  short* woT   = (short*)(ws + 70254592);           // 2 MiB  (1024 x 1024)
  short* qb    = (short*)(ws + 72351744);           // 64 MiB
  short* kb    = (short*)(ws + 139460608);          // 16 MiB
  short* vb    = (short*)(ws + 156237824);          // 16 MiB
  short* ob    = xb;                                // alias: xb dead after k_qkv

  k_prep<<<6656, 256, 0, stream>>>(x, xb, wq, wk, wv, wo, wqkvT, woT);
  k_qkv<<<768, 512, 0, stream>>>(xb, wqkvT, qs, ks, rc, rs, qb, kb, vb);
  k_attn<<<256, 512, 0, stream>>>(qb, kb, vb, ob);
  k_out<<<512, 512, 0, stream>>>(ob, woT, out);
}

// Round 15
// 314.853 us; speedup vs baseline: 1.3649x; 1.0009x over previous
//
#include <hip/hip_runtime.h>
#include <hip/hip_bf16.h>

// Problem constants
#define DM   1024
#define NHQ  16
#define NKVH 4
#define HDIM 64
#define TTT  64
#define SSS  256
#define NBB  2
#define MROWS 32768   // NBB*SSS*TTT

using short8 = __attribute__((ext_vector_type(8))) short;
using short4v = __attribute__((ext_vector_type(4))) short;
using f32x4  = __attribute__((ext_vector_type(4))) float;

__device__ __forceinline__ short f2bf(float f) {
  union { __hip_bfloat16 h; short s; } u;
  u.h = __float2bfloat16(f);
  return u.s;
}

__device__ __forceinline__ f32x4 mfma16(short8 a, short8 b, f32x4 c) {
  return __builtin_amdgcn_mfma_f32_16x16x32_bf16(a, b, c, 0, 0, 0);
}

__device__ __forceinline__ void gload_lds16(const void* g, void* l) {
  __builtin_amdgcn_global_load_lds(
      (const __attribute__((address_space(1))) void*)g,
      (__attribute__((address_space(3))) void*)l, 16, 0, 0);
}

// ---------------------------------------------------------------
// Kernel 0: merged prep. Weight transposes FIRST (latency-bound, hide
// under the BW-bound xconv bulk; k_qkv needs wqkvT done early):
// blocks [0,2560): weight transposes ; [2560,6656): xconv (8 rows/block)
// ---------------------------------------------------------------
__global__ __launch_bounds__(256) void k_prep(const float* __restrict__ x,
                                              short* __restrict__ xb,
                                              const float* __restrict__ wq,
                                              const float* __restrict__ wk,
                                              const float* __restrict__ wv,
                                              const float* __restrict__ wo,
                                              short* __restrict__ wqkvT,
                                              short* __restrict__ woT) {
  __shared__ float tile[32][33];
  int bid = blockIdx.x;
  if (bid >= 2560) {
    int cb = bid - 2560;
    float4 v[8];
    #pragma unroll
    for (int i = 0; i < 8; ++i) {
      int r = cb * 8 + i;
      int n = r >> 6, t = r & 63;
      int b = n >> 8, s = n & 255;
      v[i] = ((const float4*)(x + ((size_t)((b * TTT + t) * SSS + s)) * DM))[threadIdx.x];
    }
    #pragma unroll
    for (int i = 0; i < 8; ++i) {
      int r = cb * 8 + i;
      short4 o;
      o.x = f2bf(v[i].x); o.y = f2bf(v[i].y); o.z = f2bf(v[i].z); o.w = f2bf(v[i].w);
      ((short4*)(xb + (size_t)r * DM))[threadIdx.x] = o;
    }
    return;
  }
  const float* w; short* wt; int cols;
  if (bid < 1024)      { w = wq; wt = wqkvT; cols = 1024; }
  else if (bid < 1280) { w = wk; wt = wqkvT + (size_t)1024 * 1024; cols = 256; bid -= 1024; }
  else if (bid < 1536) { w = wv; wt = wqkvT + (size_t)1280 * 1024; cols = 256; bid -= 1280; }
  else                 { w = wo; wt = woT; cols = 1024; bid -= 1536; }
  int ctiles = cols >> 5;
  int tj = bid % ctiles;
  int td = bid / ctiles;
  int lx = threadIdx.x & 31, ly = threadIdx.x >> 5;
  #pragma unroll
  for (int rr = 0; rr < 32; rr += 8)
    tile[rr + ly][lx] = w[(size_t)(td * 32 + rr + ly) * cols + tj * 32 + lx];
  __syncthreads();
  #pragma unroll
  for (int rr = 0; rr < 32; rr += 8)
    wt[(size_t)(tj * 32 + rr + ly) * 1024 + td * 32 + lx] = f2bf(tile[lx][rr + ly]);
}

// ---------------------------------------------------------------
// 256x256 GEMM core (round-6 form, unchanged)
// ---------------------------------------------------------------
#define TILE(RAK0, RAK1, RBK0, RBK1, NLB, CLB, G, IA, IB, VM)                  \
  {                                                                            \
    short8 a[4], b0[4], b1[4];                                                 \
    _Pragma("unroll") for (int n = 0; n < 4; ++n)                              \
        b0[n] = *(const short8*)(RBK0 + n * 1024);                             \
    _Pragma("unroll") for (int m = 0; m < 4; ++m)                              \
        a[m] = *(const short8*)(RAK0 + m * 1024);                              \
    if (IA) stA0(NLB, (G + 1) * 64);                                           \
    __builtin_amdgcn_s_barrier();                                              \
    asm volatile("s_waitcnt lgkmcnt(0)" ::: "memory");                         \
    __builtin_amdgcn_s_setprio(1);                                             \
    _Pragma("unroll") for (int m = 0; m < 4; ++m)                              \
      _Pragma("unroll") for (int n = 0; n < 4; ++n)                            \
          acc[m][n] = mfma16(a[m], b0[n], acc[m][n]);                          \
    __builtin_amdgcn_s_setprio(0);                                             \
    __builtin_amdgcn_s_barrier();                                              \
    _Pragma("unroll") for (int m = 0; m < 4; ++m)                              \
        a[m] = *(const short8*)(RAK0 + 4096 + m * 1024);                       \
    if (IA) stA1(NLB, (G + 1) * 64);                                           \
    __builtin_amdgcn_s_barrier();                                              \
    asm volatile("s_waitcnt lgkmcnt(0)" ::: "memory");                         \
    __builtin_amdgcn_s_setprio(1);                                             \
    _Pragma("unroll") for (int m = 0; m < 4; ++m)                              \
      _Pragma("unroll") for (int n = 0; n < 4; ++n)                            \
          acc[4 + m][n] = mfma16(a[m], b0[n], acc[4 + m][n]);                  \
    __builtin_amdgcn_s_setprio(0);                                             \
    __builtin_amdgcn_s_barrier();                                              \
    _Pragma("unroll") for (int n = 0; n < 4; ++n)                              \
        b1[n] = *(const short8*)(RBK1 + n * 1024);                             \
    _Pragma("unroll") for (int m = 0; m < 4; ++m)                              \
        a[m] = *(const short8*)(RAK1 + m * 1024);                              \
    __builtin_amdgcn_s_barrier();                                              \
    asm volatile("s_waitcnt lgkmcnt(0)" ::: "memory");                         \
    __builtin_amdgcn_s_setprio(1);                                             \
    _Pragma("unroll") for (int m = 0; m < 4; ++m)                              \
      _Pragma("unroll") for (int n = 0; n < 4; ++n)                            \
          acc[m][n] = mfma16(a[m], b1[n], acc[m][n]);                          \
    __builtin_amdgcn_s_setprio(0);                                             \
    __builtin_amdgcn_s_barrier();                                              \
    _Pragma("unroll") for (int m = 0; m < 4; ++m)                              \
        a[m] = *(const short8*)(RAK1 + 4096 + m * 1024);                       \
    if (IB) stB(CLB, (G + 2) * 64);                                            \
    __builtin_amdgcn_s_barrier();                                              \
    asm volatile("s_waitcnt lgkmcnt(0)" ::: "memory");                         \
    __builtin_amdgcn_s_setprio(1);                                             \
    _Pragma("unroll") for (int m = 0; m < 4; ++m)                              \
      _Pragma("unroll") for (int n = 0; n < 4; ++n)                            \
          acc[4 + m][n] = mfma16(a[m], b1[n], acc[4 + m][n]);                  \
    __builtin_amdgcn_s_setprio(0);                                             \
    if (VM == 4)      asm volatile("s_waitcnt vmcnt(4)" ::: "memory");         \
    else if (VM == 0) asm volatile("s_waitcnt vmcnt(0)" ::: "memory");         \
    __builtin_amdgcn_s_barrier();                                              \
  }

__device__ __forceinline__ void gemm256(const short* __restrict__ Ab,
                                        const short* __restrict__ Bb,
                                        short* __restrict__ sm,
                                        f32x4 (&acc)[8][4]) {
  const int tid = threadIdx.x, lane = tid & 63, wid = tid >> 6;
  const int wr = wid >> 2, wc = wid & 3;
  const int ln15 = lane & 15, lhi = lane >> 4;
  const int rsw = ln15 & 7;
  const int row_t = tid >> 3;
  const int sw = ((tid & 7) ^ (row_t & 7)) << 3;
  const short* pA0 = Ab + (size_t)row_t * 1024 + sw;
  const short* pA1 = pA0 + (size_t)64 * 1024;
  const short* pA2 = pA0 + (size_t)128 * 1024;
  const short* pA3 = pA0 + (size_t)192 * 1024;
  const short* pB0 = Bb + (size_t)row_t * 1024 + sw;
  const short* pB1 = pB0 + (size_t)64 * 1024;
  const short* pB2 = pB0 + (size_t)128 * 1024;
  const short* pB3 = pB0 + (size_t)192 * 1024;
  auto stA0 = [&](short* lb, int kt) {
    gload_lds16(pA0 + kt, lb + tid * 8);
    gload_lds16(pA1 + kt, lb + 4096 + tid * 8);
  };
  auto stA1 = [&](short* lb, int kt) {
    gload_lds16(pA2 + kt, lb + 8192 + tid * 8);
    gload_lds16(pA3 + kt, lb + 12288 + tid * 8);
  };
  auto stB = [&](short* lb, int kt) {
    gload_lds16(pB0 + kt, lb + 16384 + tid * 8);
    gload_lds16(pB1 + kt, lb + 20480 + tid * 8);
    gload_lds16(pB2 + kt, lb + 24576 + tid * 8);
    gload_lds16(pB3 + kt, lb + 28672 + tid * 8);
  };
  const int sk0 = (lhi ^ rsw) << 3;
  const int sk1 = ((4 + lhi) ^ rsw) << 3;
  const short* rA0k0 = sm + (wr * 128 + ln15) * 64 + sk0;
  const short* rA0k1 = sm + (wr * 128 + ln15) * 64 + sk1;
  const short* rB0k0 = sm + 16384 + (wc * 64 + ln15) * 64 + sk0;
  const short* rB0k1 = sm + 16384 + (wc * 64 + ln15) * 64 + sk1;
  const short* rA1k0 = rA0k0 + 32768;
  const short* rA1k1 = rA0k1 + 32768;
  const short* rB1k0 = rB0k0 + 32768;
  const short* rB1k1 = rB0k1 + 32768;
  short* buf0 = sm;
  short* buf1 = sm + 32768;
  stA0(buf0, 0); stA1(buf0, 0); stB(buf0, 0);
  stA0(buf1, 64); stA1(buf1, 64); stB(buf1, 64);
  asm volatile("s_waitcnt vmcnt(8)" ::: "memory");
  __builtin_amdgcn_s_barrier();
  TILE(rA0k0, rA0k1, rB0k0, rB0k1, buf1, buf0, 0, 0, 1, 4)
  TILE(rA1k0, rA1k1, rB1k0, rB1k1, buf0, buf1, 1, 1, 1, 4)
  for (int gg = 1; gg < 7; ++gg) {
    const int g0 = gg * 2;
    TILE(rA0k0, rA0k1, rB0k0, rB0k1, buf1, buf0, g0, 1, 1, 4)
    TILE(rA1k0, rA1k1, rB1k0, rB1k1, buf0, buf1, g0 + 1, 1, 1, 4)
  }
  TILE(rA0k0, rA0k1, rB0k0, rB0k1, buf1, buf0, 14, 1, 0, 0)
  TILE(rA1k0, rA1k1, rB1k0, rB1k1, buf0, buf1, 15, 0, 0, -1)
}

// ---------------------------------------------------------------
// Kernel 1: QKV projection + RMSNorm + RoPE (round-14 form, padded epilogue)
// ---------------------------------------------------------------
__global__ __launch_bounds__(512) void k_qkv(
    const short* __restrict__ xb, const short* __restrict__ wt,
    const float* __restrict__ qscale, const float* __restrict__ kscale,
    const float* __restrict__ rcos, const float* __restrict__ rsin,
    short* __restrict__ qb, short* __restrict__ kb, short* __restrict__ vb) {
  __shared__ __align__(16) short sm[67584];   // 132 KiB (GEMM uses first 128 KiB)
  const int bid = blockIdx.x;
  const int swz = (bid & 7) * 96 + (bid >> 3);
  const int tn = swz % 6, tm = swz / 6;
  f32x4 acc[8][4] = {};
  gemm256(xb + (size_t)tm * 256 * 1024, wt + (size_t)tn * 256 * 1024, sm, acc);

  const int tid = threadIdx.x, lane = tid & 63, wid = tid >> 6;
  const int wr = wid >> 2, wc = wid & 3;
  const int ln15 = lane & 15, lhi = lane >> 4;
  short* ot = sm;                             // [256][264] padded
  if (tn < 5) {
    const float* scale = (tn < 4) ? qscale : kscale;
    float sc[4];
    #pragma unroll
    for (int n = 0; n < 4; ++n) sc[n] = scale[n * 16 + ln15];
    #pragma unroll
    for (int m = 0; m < 8; ++m) {
      #pragma unroll
      for (int j = 0; j < 4; ++j) {
        float ss = 0.f;
        #pragma unroll
        for (int n = 0; n < 4; ++n) { float v = acc[m][n][j]; ss += v * v; }
        #pragma unroll
        for (int off = 8; off; off >>= 1) ss += __shfl_xor(ss, off, 64);
        float rms = rsqrtf(ss * (1.f / 64.f) + 1e-6f);
        int rl = wr * 128 + m * 16 + lhi * 4 + j;
        int t = (tm * 256 + rl) & 63;
        #pragma unroll
        for (int n = 0; n < 2; ++n) {
          int i = n * 16 + ln15;
          float cs = rcos[t * 32 + i], sn = rsin[t * 32 + i];
          float v1 = acc[m][n][j] * rms * sc[n];
          float v2 = acc[m][n + 2][j] * rms * sc[n + 2];
          ot[rl * 264 + wc * 64 + i]      = f2bf(v1 * cs - v2 * sn);
          ot[rl * 264 + wc * 64 + i + 32] = f2bf(v1 * sn + v2 * cs);
        }
      }
    }
  } else {
    #pragma unroll
    for (int m = 0; m < 8; ++m)
      #pragma unroll
      for (int n = 0; n < 4; ++n)
        #pragma unroll
        for (int j = 0; j < 4; ++j) {
          int rl = wr * 128 + m * 16 + lhi * 4 + j;
          ot[rl * 264 + wc * 64 + n * 16 + ln15] = f2bf(acc[m][n][j]);
        }
  }
  __syncthreads();
  {
    int row = tid >> 1, half = tid & 1;
    int r = tm * 256 + row;
    const uint4* src = (const uint4*)(ot + row * 264 + half * 128);
    short* dst;
    if (tn < 4)       dst = qb + (size_t)r * 1024 + tn * 256 + half * 128;
    else if (tn == 4) dst = kb + (size_t)r * 256 + half * 128;
    else              dst = vb + (size_t)r * 256 + half * 128;
    uint4* d4 = (uint4*)dst;
    #pragma unroll
    for (int i = 0; i < 16; ++i) d4[i] = src[i];
  }
}

// ---------------------------------------------------------------
// Kernel 2: attention, TWO sequences per block (round-11 form, unchanged)
// ---------------------------------------------------------------
__global__ __launch_bounds__(512) void k_attn(const short* __restrict__ qb,
                                              const short* __restrict__ kb,
                                              const short* __restrict__ vb,
                                              short* __restrict__ ob) {
  __shared__ __align__(16) short Vt[2][256 * 72];   // 72 KiB  [c][s] per seq
  __shared__ __align__(16) short Ps[8][64 * 72];    // 72 KiB  per-wave P / O staging
  const int n0 = blockIdx.x * 2;
  const int tid = threadIdx.x, lane = tid & 63, wid = tid >> 6;
  const int ln15 = lane & 15, lhi = lane >> 4;
  short8 vr0[4], vr1[4];
  {
    const short* vrow0 = vb + ((size_t)(n0 * 64 + lane)) * 256;
    const short* vrow1 = vrow0 + 64 * 256;
    #pragma unroll
    for (int i = 0; i < 4; ++i) vr1[i] = *(const short8*)(vrow1 + wid * 32 + i * 8);
    #pragma unroll
    for (int i = 0; i < 4; ++i) vr0[i] = *(const short8*)(vrow0 + wid * 32 + i * 8);
  }
  #pragma unroll
  for (int i = 0; i < 4; ++i) {
    int d = wid * 32 + i * 8;
    #pragma unroll
    for (int e = 0; e < 8; ++e) Vt[0][(d + e) * 72 + lane] = vr0[i][e];
  }
  short* Pt = &Ps[wid][0];
  #pragma unroll
  for (int ss = 0; ss < 2; ++ss) {
    const int n = n0 + ss;
    if (ss == 1) {
      #pragma unroll
      for (int i = 0; i < 4; ++i) {
        int d = wid * 32 + i * 8;
        #pragma unroll
        for (int e = 0; e < 8; ++e) Vt[1][(d + e) * 72 + lane] = vr1[i][e];
      }
    }
    short8 aq[2][4][2];
    #pragma unroll
    for (int hh = 0; hh < 2; ++hh)
      #pragma unroll
      for (int nn = 0; nn < 4; ++nn)
        #pragma unroll
        for (int kk = 0; kk < 2; ++kk)
          aq[hh][nn][kk] = *(const short8*)(qb + ((size_t)(n * 64 + nn * 16 + ln15)) * 1024
                                               + (wid + hh * 8) * 64 + kk * 32 + lhi * 8);
    __syncthreads();
    const short* Vts = &Vt[ss][0];
    #pragma unroll
    for (int hh = 0; hh < 2; ++hh) {
      const int h = wid + hh * 8;
      const int kvh = h >> 2;
      short8 bk[4][2];
      #pragma unroll
      for (int m = 0; m < 4; ++m)
        #pragma unroll
        for (int kk = 0; kk < 2; ++kk)
          bk[m][kk] = *(const short8*)(kb + ((size_t)(n * 64 + m * 16 + ln15)) * 256
                                          + kvh * 64 + kk * 32 + lhi * 8);
      f32x4 sa[4][4] = {};
      __builtin_amdgcn_s_setprio(1);
      #pragma unroll
      for (int kk = 0; kk < 2; ++kk)
        #pragma unroll
        for (int m = 0; m < 4; ++m)
          #pragma unroll
          for (int nn = 0; nn < 4; ++nn)
            sa[m][nn] = mfma16(bk[m][kk], aq[hh][nn][kk], sa[m][nn]);
      __builtin_amdgcn_s_setprio(0);
      #pragma unroll
      for (int m = 0; m < 4; ++m)
        #pragma unroll
        for (int nn = 0; nn < 4; ++nn)
          #pragma unroll
          for (int j = 0; j < 4; ++j) {
            float e2 = __expf(sa[m][nn][j] * 0.005f);
            float cap = 50.f * (e2 - 1.f) * __builtin_amdgcn_rcpf(e2 + 1.f);
            int scur = m * 16 + lhi * 4 + j, tcur = nn * 16 + ln15;
            sa[m][nn][j] = (scur <= tcur) ? cap : -1e30f;
          }
      float inv[4];
      #pragma unroll
      for (int nn = 0; nn < 4; ++nn) {
        float mx = -3e38f;
        #pragma unroll
        for (int m = 0; m < 4; ++m)
          #pragma unroll
          for (int j = 0; j < 4; ++j) mx = fmaxf(mx, sa[m][nn][j]);
        mx = fmaxf(mx, __shfl_xor(mx, 16, 64));
        mx = fmaxf(mx, __shfl_xor(mx, 32, 64));
        float sum = 0.f;
        #pragma unroll
        for (int m = 0; m < 4; ++m)
          #pragma unroll
          for (int j = 0; j < 4; ++j) {
            float e = __expf(sa[m][nn][j] - mx);
            sa[m][nn][j] = e; sum += e;
          }
        sum += __shfl_xor(sum, 16, 64);
        sum += __shfl_xor(sum, 32, 64);
        inv[nn] = __builtin_amdgcn_rcpf(sum);
      }
      #pragma unroll
      for (int nn = 0; nn < 4; ++nn)
        #pragma unroll
        for (int m = 0; m < 4; ++m) {
          short4v w;
          #pragma unroll
          for (int j = 0; j < 4; ++j) w[j] = f2bf(sa[m][nn][j] * inv[nn]);
          *(short4v*)(Pt + (nn * 16 + ln15) * 72 + m * 16 + lhi * 4) = w;
        }
      short8 ap[4][2], bv[4][2];
      #pragma unroll
      for (int m = 0; m < 4; ++m)
        #pragma unroll
        for (int kk = 0; kk < 2; ++kk)
          ap[m][kk] = *(const short8*)(Pt + (m * 16 + ln15) * 72 + kk * 32 + lhi * 8);
      #pragma unroll
      for (int nn = 0; nn < 4; ++nn)
        #pragma unroll
        for (int kk = 0; kk < 2; ++kk)
          bv[nn][kk] = *(const short8*)(Vts + (kvh * 64 + nn * 16 + ln15) * 72 + kk * 32 + lhi * 8);
      f32x4 oa[4][4] = {};
      __builtin_amdgcn_s_setprio(1);
      #pragma unroll
      for (int kk = 0; kk < 2; ++kk)
        #pragma unroll
        for (int m = 0; m < 4; ++m)
          #pragma unroll
          for (int nn = 0; nn < 4; ++nn)
            oa[m][nn] = mfma16(ap[m][kk], bv[nn][kk], oa[m][nn]);
      __builtin_amdgcn_s_setprio(0);
      #pragma unroll
      for (int m = 0; m < 4; ++m)
        #pragma unroll
        for (int nn = 0; nn < 4; ++nn)
          #pragma unroll
          for (int j = 0; j < 4; ++j)
            Pt[(m * 16 + lhi * 4 + j) * 72 + nn * 16 + ln15] = f2bf(oa[m][nn][j]);
      #pragma unroll
      for (int c = 0; c < 8; ++c)
        *(uint4*)(ob + ((size_t)(n * 64 + lane)) * 1024 + h * 64 + c * 8)
            = *(const uint4*)(Pt + lane * 72 + c * 8);
    }
  }
}

// ---------------------------------------------------------------
// Kernel 3: output projection + scatter to (B,T,S,D) f32 (round-14 form)
// ---------------------------------------------------------------
__global__ __launch_bounds__(512) void k_out(const short* __restrict__ ab,
                                             const short* __restrict__ wt,
                                             float* __restrict__ out) {
  __shared__ __align__(16) short sm[66560];   // 130 KiB (GEMM uses first 128 KiB)
  const int bid = blockIdx.x;
  const int swz = (bid & 7) * 64 + (bid >> 3);
  const int tn = swz & 3, tm = swz >> 2;
  f32x4 acc[8][4] = {};
  gemm256(ab + (size_t)tm * 256 * 1024, wt + (size_t)tn * 256 * 1024, sm, acc);

  const int tid = threadIdx.x, lane = tid & 63, wid = tid >> 6;
  const int wr = wid >> 2, wc = wid & 3;
  const int ln15 = lane & 15, lhi = lane >> 4;
  float* of = (float*)sm;                     // [128][260] padded
  #pragma unroll
  for (int ch = 0; ch < 2; ++ch) {
    if (wr == ch) {
      #pragma unroll
      for (int m = 0; m < 8; ++m)
        #pragma unroll
        for (int n = 0; n < 4; ++n)
          #pragma unroll
          for (int j = 0; j < 4; ++j)
            of[(m * 16 + lhi * 4 + j) * 260 + wc * 64 + n * 16 + ln15] = acc[m][n][j];
    }
    __syncthreads();
    {
      int row = tid >> 2, q4 = tid & 3;
      int r = tm * 256 + ch * 128 + row;
      int nseq = r >> 6, t = r & 63;
      int b = nseq >> 8, s = nseq & 255;
      float* dst = out + ((size_t)((b * TTT + t) * SSS + s)) * DM + tn * 256 + q4 * 64;
      const float4* src = (const float4*)(of + row * 260 + q4 * 64);
      float4* d4 = (float4*)dst;
      #pragma unroll
      for (int i = 0; i < 16; ++i) d4[i] = src[i];
    }
    __syncthreads();
  }
}

// ---------------------------------------------------------------
extern "C" void kernel_launch(void* const* d_in, const int* in_sizes, int n_in,
                              void* d_out, int out_size, void* d_ws, size_t ws_size,
                              hipStream_t stream) {
  const float* x  = (const float*)d_in[0];
  const float* wq = (const float*)d_in[1];
  const float* wk = (const float*)d_in[2];
  const float* wv = (const float*)d_in[3];
  const float* wo = (const float*)d_in[4];
  const float* qs = (const float*)d_in[5];
  const float* ks = (const float*)d_in[6];
  const float* rc = (const float*)d_in[7];
  const float* rs = (const float*)d_in[8];
  float* out = (float*)d_out;
  char* ws = (char*)d_ws;

  short* xb    = (short*)(ws);                      // 64 MiB; later aliased as attn-out
  short* wqkvT = (short*)(ws + 67108864);           // 3 MiB  (1536 x 1024)
  short* woT   = (short*)(ws + 70254592);           // 2 MiB  (1024 x 1024)
  short* qb    = (short*)(ws + 72351744);           // 64 MiB
  short* kb    = (short*)(ws + 139460608);          // 16 MiB
  short* vb    = (short*)(ws + 156237824);          // 16 MiB
  short* ob    = xb;                                // alias: xb dead after k_qkv

  k_prep<<<6656, 256, 0, stream>>>(x, xb, wq, wk, wv, wo, wqkvT, woT);
  k_qkv<<<768, 512, 0, stream>>>(xb, wqkvT, qs, ks, rc, rs, qb, kb, vb);
  k_attn<<<256, 512, 0, stream>>>(qb, kb, vb, ob);
  k_out<<<512, 512, 0, stream>>>(ob, woT, out);
}